// Round 7
// baseline (1025.702 us; speedup 1.0000x reference)
//
#include <hip/hip_runtime.h>

// Padded layout for all intermediates: [N][C][30][32] floats.
// Row 0 / row 29 are y-halos; col 0 / col 29 are x-halos (zero); cols 30,31 pad.
// Element (y,x) of the logical 28x28 image lives at [y+1][x+1].
#define PADH 30
#define PADW 32
#define CSTR (PADH*PADW)            // 960 floats per channel
#define NIMG 32
#define NCH  128
#define HW   28
#define PBUF ((size_t)NIMG*NCH*CSTR)   // 3,932,160 floats per padded buffer
#define WREL (128*128*9)               // 147456 weights per tensor

typedef float wf4 __attribute__((ext_vector_type(4)));
// Constant-address-space view of the weight slice: block-uniform address ->
// compiler emits s_load (SGPR broadcast), with its own waitcnt/spill handling.
typedef __attribute__((address_space(4))) const wf4 cwf4;

// ---------------------------------------------------------------------------
// Quantize shift weights (sign * 2^round(log2|w|), zeroed below 0.005) and
// reorganize all 4 weight tensors to [cog32(32)][ci(128)][tap(9)][co4(4)]:
// one ci's weights for a 4-channel group = 36 consecutive floats (144 B).
__global__ __launch_bounds__(256) void prep_weights(
    const float* __restrict__ s1, const float* __restrict__ a1,
    const float* __restrict__ s2, const float* __restrict__ a2,
    float* __restrict__ dst) {
  int gid = blockIdx.x * 256 + threadIdx.x;          // 4*147456 threads
  int t = gid / WREL, r = gid % WREL;
  const float* src = (t == 0) ? s1 : (t == 1) ? a1 : (t == 2) ? s2 : a2;
  float v = src[r];
  if ((t & 1) == 0) {                                // t=0,2: shift weights
    float aw = fabsf(v);
    if (aw < 0.005f) {
      v = 0.0f;
    } else {
      int e; float m = frexpf(aw, &e);               // aw = m*2^e, m in [0.5,1)
      int k = (m >= 0.70710678f) ? e : e - 1;        // round(log2 aw)
      v = ldexpf(copysignf(1.0f, v), k);             // exact power of two
    }
  }
  // source layout [co][ci][3][3]
  int co = r / 1152, rem = r % 1152;
  int ci = rem / 9, tap = rem % 9;
  int cog = co >> 2, j = co & 3;
  dst[(size_t)t * WREL + (((cog * 128 + ci) * 9 + tap) << 2) + j] = v;
}

// ---------------------------------------------------------------------------
// x (compact NCHW) -> padded buffer with zero halos.  983040 float4 threads.
__global__ __launch_bounds__(256) void pad_copy(
    const float* __restrict__ x, float* __restrict__ o) {
  int idx = blockIdx.x * 256 + threadIdx.x;          // 983040 threads (PBUF/4)
  int f = idx * 4;
  int n = f / (NCH * CSTR);
  int c = (f / CSTR) % NCH;
  int o960 = f % CSTR;
  int r = o960 >> 5, col = o960 & 31;
  float4 out;
  float vals[4];
#pragma unroll
  for (int k = 0; k < 4; ++k) {
    int cc = col + k;
    bool inside = (r >= 1 && r <= HW && cc >= 1 && cc <= HW);
    vals[k] = inside ? x[(size_t)(n * NCH + c) * (HW * HW) + (r - 1) * HW + (cc - 1)]
                     : 0.0f;
  }
  out.x = vals[0]; out.y = vals[1]; out.z = vals[2]; out.w = vals[3];
  *(float4*)(o + f) = out;
}

// Zero the halo cells of a padded buffer (rows 0/29 fully, cols 0/29 of rows 1..28).
__global__ __launch_bounds__(256) void zero_halo(float* __restrict__ b) {
  int gid = blockIdx.x * 256 + threadIdx.x;          // 4096*120 threads
  int nc = gid / 120, i = gid % 120;
  float* p = b + (size_t)nc * CSTR;
  if (i < 64) {
    int row = (i < 32) ? 0 : (PADH - 1);
    p[row * PADW + (i & 31)] = 0.0f;
  } else {
    int i2 = i - 64;                                  // 56 entries: rows 1..28 x {0,29}
    int row = 1 + (i2 >> 1);
    int col = (i2 & 1) ? (HW + 1) : 0;
    p[row * PADW + col] = 0.0f;
  }
}

// ---------------------------------------------------------------------------
// Load one ci's 3 input rows (4 padded cols) into registers. 8B-aligned float2s.
__device__ __forceinline__ void load_rows(const float* __restrict__ p,
                                          float r[3][4]) {
#pragma unroll
  for (int ky = 0; ky < 3; ++ky) {
    float2 a = *(const float2*)(p + ky * PADW);
    float2 b = *(const float2*)(p + ky * PADW + 2);
    r[ky][0] = a.x; r[ky][1] = a.y; r[ky][2] = b.x; r[ky][3] = b.y;
  }
}

// 3x3 conv, stride 1. ADDER=0: out = sum w*in (shift conv, w pre-quantized).
// ADDER=1: out = -sum |in - w| (AdderNet).
// No LDS. Weights are block-uniform -> read through a constant-AS pointer so
// the compiler emits s_load into SGPRs (free VALU operand, no VMEM traffic).
// Thread: 2 px x 4 co. Block 256. Grid 1568 = 8 XCD x 196 (bijective
// swizzle): each XCD covers a contiguous spatial range x all 32 cogs, so its
// input slab (~2 MB) + weights (576 KB) stay in its 4 MiB L2.
template<int ADDER>
__global__ __launch_bounds__(256) void conv3x3(
    const float* __restrict__ in, const float* __restrict__ wr,
    float* __restrict__ out) {
  int bid = blockIdx.x;
  int v = (bid & 7) * 196 + (bid >> 3);               // XCD-contiguous remap
  int cog = v & 31;                                   // 32 groups of 4 co
  int chunk = v >> 5;                                 // 0..48
  int tid = threadIdx.x;

  int wi = chunk * 256 + tid;                         // 0..12543
  int xh = wi % 14;
  int r2 = wi / 14;
  int y = r2 % 28;
  int n = r2 / 28;
  int x0 = xh << 1;                                   // pixels x0, x0+1
  const float* ib = in + (size_t)n * NCH * CSTR + y * PADW + x0;
  cwf4* w4 = (cwf4*)(wr + (size_t)cog * 4608);        // [ci][tap(9)][co4]

  float acc[4][2];
#pragma unroll
  for (int j = 0; j < 4; ++j) { acc[j][0] = 0.0f; acc[j][1] = 0.0f; }

#pragma unroll 2
  for (int ci = 0; ci < 128; ++ci) {
    float rv[3][4];                                   // rows y-1..y+1, cols x0-1..x0+2
    load_rows(ib, rv);
    wf4 wv[9];
#pragma unroll
    for (int t = 0; t < 9; ++t) wv[t] = w4[ci * 9 + t];
#pragma unroll
    for (int ky = 0; ky < 3; ++ky)
#pragma unroll
      for (int kx = 0; kx < 3; ++kx) {
        wf4 w = wv[ky * 3 + kx];
#pragma unroll
        for (int p = 0; p < 2; ++p) {
          float val = rv[ky][kx + p];
          if (ADDER) {
            acc[0][p] += fabsf(val - w.x);
            acc[1][p] += fabsf(val - w.y);
            acc[2][p] += fabsf(val - w.z);
            acc[3][p] += fabsf(val - w.w);
          } else {
            acc[0][p] = fmaf(val, w.x, acc[0][p]);
            acc[1][p] = fmaf(val, w.y, acc[1][p]);
            acc[2][p] = fmaf(val, w.z, acc[2][p]);
            acc[3][p] = fmaf(val, w.w, acc[3][p]);
          }
        }
      }
    ib += CSTR;
  }

  float* ob = out + ((size_t)(n * NCH + (cog << 2)) * PADH + (y + 1)) * PADW + (x0 + 1);
#pragma unroll
  for (int j = 0; j < 4; ++j) {
    ob[j * CSTR + 0] = ADDER ? -acc[j][0] : acc[j][0];
    ob[j * CSTR + 1] = ADDER ? -acc[j][1] : acc[j][1];
  }
}

// ---------------------------------------------------------------------------
// Batch stats per channel (training-mode BN), double accumulation to avoid
// E[x^2]-mean^2 cancellation. Deterministic tree reduction.
// Emits sb[c] = gamma*rstd, sb[128+c] = beta - mean*gamma*rstd.
__global__ __launch_bounds__(256) void bn_stats(
    const float* __restrict__ t, const float* __restrict__ gamma,
    const float* __restrict__ beta, float* __restrict__ sb) {
  int c = blockIdx.x;
  int tid = threadIdx.x;
  double s = 0.0, s2 = 0.0;
  for (int i = tid; i < NIMG * HW * HW; i += 256) {
    int n = i / (HW * HW);
    int rem = i % (HW * HW);
    int r = rem / HW, x = rem % HW;
    float v = t[((size_t)(n * NCH + c) * PADH + r + 1) * PADW + x + 1];
    s += v; s2 += (double)v * v;
  }
  __shared__ double sd[256], sq[256];
  sd[tid] = s; sq[tid] = s2;
  __syncthreads();
  for (int off = 128; off > 0; off >>= 1) {
    if (tid < off) { sd[tid] += sd[tid + off]; sq[tid] += sq[tid + off]; }
    __syncthreads();
  }
  if (tid == 0) {
    double cnt = (double)(NIMG * HW * HW);
    double mean = sd[0] / cnt;
    double var = sq[0] / cnt - mean * mean;
    double rstd = 1.0 / sqrt(var + 1e-5);
    double g = (double)gamma[c];
    sb[c] = (float)(g * rstd);
    sb[NCH + c] = (float)((double)beta[c] - mean * g * rstd);
  }
}

// BN apply + ReLU over the FULL padded grid (halos -> 0, which is exactly the
// zero-padding the next conv needs).
__global__ __launch_bounds__(256) void bn_apply_relu(
    const float* __restrict__ t, const float* __restrict__ sb,
    float* __restrict__ o) {
  int idx = blockIdx.x * 256 + threadIdx.x;          // 983040 threads (PBUF/4)
  int f = idx * 4;
  int c = (f / CSTR) % NCH;
  int o960 = f % CSTR;
  int r = o960 >> 5, col = o960 & 31;
  float4 v = *(const float4*)(t + f);
  float sc = sb[c], bi = sb[NCH + c];
  bool rin = (r >= 1 && r <= HW);
  float in0[4] = {v.x, v.y, v.z, v.w};
  float vals[4];
#pragma unroll
  for (int k = 0; k < 4; ++k) {
    int cc = col + k;
    float val = fmaxf(fmaf(in0[k], sc, bi), 0.0f);
    vals[k] = (rin && cc >= 1 && cc <= HW) ? val : 0.0f;
  }
  float4 out; out.x = vals[0]; out.y = vals[1]; out.z = vals[2]; out.w = vals[3];
  *(float4*)(o + f) = out;
}

// Final: out = relu(bn2(t5) + residual x), compact NCHW output.
__global__ __launch_bounds__(256) void final_kernel(
    const float* __restrict__ t5, const float* __restrict__ sb,
    const float* __restrict__ x, float* __restrict__ out) {
  int idx = blockIdx.x * 256 + threadIdx.x;          // 802816 float4 threads
  int f = idx * 4;
  int n = f / (NCH * HW * HW);
  int c = (f / (HW * HW)) % NCH;
  int o = f % (HW * HW);
  int y = o / HW, xc = o % HW;                        // xc % 4 == 0, same row
  const float* tp = t5 + ((size_t)(n * NCH + c) * PADH + y + 1) * PADW + xc + 1;
  float sc = sb[c], bi = sb[NCH + c];
  float4 xv = *(const float4*)(x + f);
  float4 ov;
  ov.x = fmaxf(fmaf(tp[0], sc, bi) + xv.x, 0.0f);
  ov.y = fmaxf(fmaf(tp[1], sc, bi) + xv.y, 0.0f);
  ov.z = fmaxf(fmaf(tp[2], sc, bi) + xv.z, 0.0f);
  ov.w = fmaxf(fmaf(tp[3], sc, bi) + xv.w, 0.0f);
  *(float4*)(out + f) = ov;
}

// ---------------------------------------------------------------------------
extern "C" void kernel_launch(void* const* d_in, const int* in_sizes, int n_in,
                              void* d_out, int out_size, void* d_ws, size_t ws_size,
                              hipStream_t stream) {
  const float* x   = (const float*)d_in[0];
  const float* ws1 = (const float*)d_in[1];
  const float* wa1 = (const float*)d_in[2];
  const float* g1  = (const float*)d_in[3];
  const float* b1  = (const float*)d_in[4];
  const float* ws2 = (const float*)d_in[5];
  const float* wa2 = (const float*)d_in[6];
  const float* g2  = (const float*)d_in[7];
  const float* b2  = (const float*)d_in[8];
  float* out = (float*)d_out;

  float* w  = (float*)d_ws;
  float* P0 = w;                    // x padded, later t3
  float* P1 = w + PBUF;             // t1, later t4
  float* P2 = w + 2 * PBUF;         // t2, later t5
  float* WQ = w + 3 * PBUF;         // 4 reorganized weight tensors
  float* Q1 = WQ;
  float* A1 = WQ + WREL;
  float* Q2 = WQ + 2 * (size_t)WREL;
  float* A2 = WQ + 3 * (size_t)WREL;
  float* SB1 = WQ + 4 * (size_t)WREL;   // scale/bias layer 1 (256 floats)
  float* SB2 = SB1 + 256;

  hipLaunchKernelGGL(prep_weights, dim3(2304), dim3(256), 0, stream, ws1, wa1, ws2, wa2, WQ);
  hipLaunchKernelGGL(pad_copy,     dim3(3840), dim3(256), 0, stream, x, P0);
  hipLaunchKernelGGL(zero_halo,    dim3(1920), dim3(256), 0, stream, P1);
  hipLaunchKernelGGL((conv3x3<0>), dim3(1568), dim3(256), 0, stream, P0, Q1, P1);  // t1 = shift1(x)
  hipLaunchKernelGGL((conv3x3<1>), dim3(1568), dim3(256), 0, stream, P1, A1, P2);  // t2 = adder1(t1)
  hipLaunchKernelGGL(bn_stats,     dim3(128),  dim3(256), 0, stream, P2, g1, b1, SB1);
  hipLaunchKernelGGL(bn_apply_relu,dim3(3840), dim3(256), 0, stream, P2, SB1, P0); // t3
  hipLaunchKernelGGL((conv3x3<0>), dim3(1568), dim3(256), 0, stream, P0, Q2, P1);  // t4 = shift2(t3)
  hipLaunchKernelGGL((conv3x3<1>), dim3(1568), dim3(256), 0, stream, P1, A2, P2);  // t5 = adder2(t4)
  hipLaunchKernelGGL(bn_stats,     dim3(128),  dim3(256), 0, stream, P2, g2, b2, SB2);
  hipLaunchKernelGGL(final_kernel, dim3(3136), dim3(256), 0, stream, P2, SB2, x, out);
}

// Round 8
// 876.482 us; speedup vs baseline: 1.1702x; 1.1702x over previous
//
#include <hip/hip_runtime.h>

// Padded fp32 layout for conv tensors: [N][C][30][32], halos zero.
// Channel-last bf16 layout for MFMA inputs: [N][30][32][128] (halos zero).
#define PADH 30
#define PADW 32
#define CSTR (PADH*PADW)            // 960 floats per channel
#define NIMG 32
#define NCH  128
#define HW   28
#define PBUF ((size_t)NIMG*NCH*CSTR)   // 3,932,160
#define WREL (128*128*9)               // 147456 weights per tensor

typedef __attribute__((ext_vector_type(8))) short bf16x8;
typedef __attribute__((ext_vector_type(4))) float f32x4;

__device__ __forceinline__ unsigned short f2bf(float f) {   // RNE
  unsigned u = __float_as_uint(f);
  return (unsigned short)((u + 0x7FFFu + ((u >> 16) & 1u)) >> 16);
}

// ---------------------------------------------------------------------------
// Adder weights -> [cog16][ci(128)][tap(9)][co8] fp32 (R5 layout, LDS-staged).
__global__ __launch_bounds__(256) void prep_adder(
    const float* __restrict__ a1, const float* __restrict__ a2,
    float* __restrict__ dst) {
  int gid = blockIdx.x * 256 + threadIdx.x;          // 2*147456 threads
  int t = gid / WREL, r = gid % WREL;
  float v = (t ? a2 : a1)[r];
  int co = r / 1152, rem = r % 1152;
  int ci = rem / 9, tap = rem % 9;
  int cog = co >> 3, j = co & 7;
  dst[(size_t)t * WREL + (((cog * 128 + ci) * 9 + tap) << 3) + j] = v;
}

// Shift weights: quantize sign*2^round(log2|w|) (zero < 0.005), exact in bf16.
// Layout [cog8][tap9][co16][ci128] bf16 so the MFMA A-frag is one b128/lane.
__global__ __launch_bounds__(256) void prep_shift(
    const float* __restrict__ s1, const float* __restrict__ s2,
    unsigned short* __restrict__ dst) {
  int gid = blockIdx.x * 256 + threadIdx.x;          // 2*147456 threads
  int t = gid / WREL, r = gid % WREL;
  float v = (t ? s2 : s1)[r];
  float aw = fabsf(v);
  if (aw < 0.005f) {
    v = 0.0f;
  } else {
    int e; float m = frexpf(aw, &e);
    int k = (m >= 0.70710678f) ? e : e - 1;          // round(log2 aw)
    v = ldexpf(copysignf(1.0f, v), k);               // exact power of two
  }
  int co = r / 1152, rem = r % 1152;
  int ci = rem / 9, tap = rem % 9;
  int cog = co >> 4, cop = co & 15;
  dst[(size_t)t * WREL + (size_t)((cog * 9 + tap) * 16 + cop) * 128 + ci] = f2bf(v);
}

// ---------------------------------------------------------------------------
// x (compact NCHW fp32) -> channel-last bf16 padded [n][yp30][xp32][ci128].
// Block = (n, yp); LDS transpose tile with stride 130 (conflict-free).
__global__ __launch_bounds__(256) void pad_cl(
    const float* __restrict__ x, unsigned short* __restrict__ o) {
  __shared__ unsigned short tile[32 * 130];
  int n = blockIdx.x / PADH, yp = blockIdx.x % PADH;
  int tid = threadIdx.x;
  bool rowok = (yp >= 1 && yp <= HW);
#pragma unroll
  for (int it = 0; it < 16; ++it) {
    int idx = it * 256 + tid;                        // xp fast -> coalesced read
    int ci = idx >> 5, xp = idx & 31;
    float v = 0.0f;
    if (rowok && xp >= 1 && xp <= HW)
      v = x[(size_t)(n * NCH + ci) * (HW * HW) + (yp - 1) * HW + (xp - 1)];
    tile[xp * 130 + ci] = f2bf(v);
  }
  __syncthreads();
  unsigned int* ob = (unsigned int*)(o + (size_t)(n * PADH + yp) * PADW * NCH);
#pragma unroll
  for (int it = 0; it < 8; ++it) {
    int uidx = it * 256 + tid;                       // 2048 uints
    int xp = uidx >> 6, cj = uidx & 63;
    ob[xp * 64 + cj] = *(const unsigned int*)&tile[xp * 130 + 2 * cj];
  }
}

// t2 (fp32 padded) -> BN+ReLU -> channel-last bf16 padded (halos zero).
__global__ __launch_bounds__(256) void bn_apply_relu_cl(
    const float* __restrict__ t, const float* __restrict__ sb,
    unsigned short* __restrict__ o) {
  __shared__ unsigned short tile[32 * 130];
  int n = blockIdx.x / PADH, yp = blockIdx.x % PADH;
  int tid = threadIdx.x;
  bool rowok = (yp >= 1 && yp <= HW);
#pragma unroll
  for (int it = 0; it < 16; ++it) {
    int idx = it * 256 + tid;
    int ci = idx >> 5, xp = idx & 31;
    float v = 0.0f;
    if (rowok && xp >= 1 && xp <= HW) {
      float tv = t[((size_t)(n * NCH + ci) * PADH + yp) * PADW + xp];
      v = fmaxf(fmaf(tv, sb[ci], sb[NCH + ci]), 0.0f);
    }
    tile[xp * 130 + ci] = f2bf(v);
  }
  __syncthreads();
  unsigned int* ob = (unsigned int*)(o + (size_t)(n * PADH + yp) * PADW * NCH);
#pragma unroll
  for (int it = 0; it < 8; ++it) {
    int uidx = it * 256 + tid;
    int xp = uidx >> 6, cj = uidx & 63;
    ob[xp * 64 + cj] = *(const unsigned int*)&tile[xp * 130 + 2 * cj];
  }
}

// Zero halo cells of a padded fp32 buffer (once; convs write interior only).
__global__ __launch_bounds__(256) void zero_halo(float* __restrict__ b) {
  int gid = blockIdx.x * 256 + threadIdx.x;          // 4096*120 threads
  int nc = gid / 120, i = gid % 120;
  float* p = b + (size_t)nc * CSTR;
  if (i < 64) {
    int row = (i < 32) ? 0 : (PADH - 1);
    p[row * PADW + (i & 31)] = 0.0f;
  } else {
    int i2 = i - 64;
    int row = 1 + (i2 >> 1);
    int col = (i2 & 1) ? (HW + 1) : 0;
    p[row * PADW + col] = 0.0f;
  }
}

// ---------------------------------------------------------------------------
// Shift conv on matrix cores. D[co16][px16] = sum_k W[co][k] * In[k][px],
// k = tap*128 + ci. Wave = one (n, px-tile, co-tile); 36 x mfma 16x16x32 bf16.
// A-frag: lane: co=l&15, k=(l>>4)*8+j -> w[cog][tap][co][ci] one b128.
// B-frag: lane: px=l&15, same k     -> in[n][y+ky][x+kx][ci] one b128.
// D: col(px)=l&15, row(co)=(l>>4)*4+reg [verified mapping].
__global__ __launch_bounds__(256) void shift_mfma(
    const unsigned short* __restrict__ in, const unsigned short* __restrict__ wq,
    float* __restrict__ out) {
  int wg = blockIdx.x * 4 + (threadIdx.x >> 6);      // 0..12543
  int lane = threadIdx.x & 63;
  int cot = wg & 7;
  int rem = wg >> 3;                                 // 0..1567
  int pxt = rem % 49;
  int n = rem / 49;
  int px = pxt * 16 + (lane & 15);
  int y = px / HW, x = px % HW;
  int kg = lane >> 4;                                // 0..3

  const unsigned short* ibase =
      in + ((size_t)(n * PADH + y + 1) * PADW + (x + 1)) * NCH + kg * 8;
  const unsigned short* wbase =
      wq + ((size_t)(cot * 9) * 16 + (lane & 15)) * NCH + kg * 8;

  f32x4 acc = {0.f, 0.f, 0.f, 0.f};
#pragma unroll
  for (int tap = 0; tap < 9; ++tap) {
    const int ky = tap / 3 - 1, kx = tap % 3 - 1;
    const unsigned short* ib = ibase + (ky * PADW + kx) * NCH;
    const unsigned short* wb = wbase + (size_t)tap * 16 * NCH;
#pragma unroll
    for (int kc = 0; kc < 4; ++kc) {
      bf16x8 a = *(const bf16x8*)(wb + kc * 32);
      bf16x8 b = *(const bf16x8*)(ib + kc * 32);
      acc = __builtin_amdgcn_mfma_f32_16x16x32_bf16(a, b, acc, 0, 0, 0);
    }
  }
  int coa = cot * 16 + (lane >> 4) * 4;
  float* ob = out + ((size_t)(n * NCH + coa) * PADH + (y + 1)) * PADW + (x + 1);
#pragma unroll
  for (int r = 0; r < 4; ++r) ob[r * CSTR] = acc[r];
}

// ---------------------------------------------------------------------------
// AdderNet conv (R5 bench-best): out = -sum |in - w|. LDS weight slice 36 KB,
// 2px x 8co per thread, XCD swizzle, 2-deep ci pipeline.
__device__ __forceinline__ void load_rows(const float* __restrict__ p,
                                          float r[3][4]) {
#pragma unroll
  for (int ky = 0; ky < 3; ++ky) {
    float2 a = *(const float2*)(p + ky * PADW);
    float2 b = *(const float2*)(p + ky * PADW + 2);
    r[ky][0] = a.x; r[ky][1] = a.y; r[ky][2] = b.x; r[ky][3] = b.y;
  }
}

__device__ __forceinline__ void adder_ci(const float r[3][4],
                                         const float4* __restrict__ wv,
                                         float acc[8][2]) {
#pragma unroll
  for (int ky = 0; ky < 3; ++ky)
#pragma unroll
    for (int kx = 0; kx < 3; ++kx) {
      float4 wA = wv[(ky * 3 + kx) * 2];
      float4 wB = wv[(ky * 3 + kx) * 2 + 1];
#pragma unroll
      for (int p = 0; p < 2; ++p) {
        float v = r[ky][kx + p];
        acc[0][p] += fabsf(v - wA.x);
        acc[1][p] += fabsf(v - wA.y);
        acc[2][p] += fabsf(v - wA.z);
        acc[3][p] += fabsf(v - wA.w);
        acc[4][p] += fabsf(v - wB.x);
        acc[5][p] += fabsf(v - wB.y);
        acc[6][p] += fabsf(v - wB.z);
        acc[7][p] += fabsf(v - wB.w);
      }
    }
}

__global__ __launch_bounds__(256, 4) void adder_conv(
    const float* __restrict__ in, const float* __restrict__ wr,
    float* __restrict__ out) {
  __shared__ float4 ws[2304];                        // 128 ci * 18 float4 = 36 KB
  int bid = blockIdx.x;
  int v = (bid & 7) * 98 + (bid >> 3);               // XCD-contiguous remap (784=8*98)
  int cog = v & 15;
  int chunk = v >> 4;                                // 0..48
  int tid = threadIdx.x;
  const float4* src4 = (const float4*)(wr + (size_t)cog * 9216);
#pragma unroll
  for (int k = 0; k < 9; ++k) ws[k * 256 + tid] = src4[k * 256 + tid];
  __syncthreads();

  int wi = chunk * 256 + tid;                        // 0..12543
  int xh = wi % 14;
  int r2 = wi / 14;
  int y = r2 % 28;
  int n = r2 / 28;
  int x0 = xh << 1;
  const float* ib = in + (size_t)n * NCH * CSTR + y * PADW + x0;
  float acc[8][2];
#pragma unroll
  for (int j = 0; j < 8; ++j) { acc[j][0] = 0.0f; acc[j][1] = 0.0f; }

  float ra[3][4], rb[3][4];
  load_rows(ib, ra);
  for (int ci = 0; ci < 128; ci += 2) {
    load_rows(ib + CSTR, rb);
    adder_ci(ra, ws + ci * 18, acc);
    if (ci + 2 < 128) load_rows(ib + 2 * CSTR, ra);
    adder_ci(rb, ws + (ci + 1) * 18, acc);
    ib += 2 * CSTR;
  }

  float* ob = out + ((size_t)(n * NCH + (cog << 3)) * PADH + (y + 1)) * PADW + (x0 + 1);
#pragma unroll
  for (int j = 0; j < 8; ++j) {
    ob[j * CSTR + 0] = -acc[j][0];
    ob[j * CSTR + 1] = -acc[j][1];
  }
}

// ---------------------------------------------------------------------------
// BN batch stats (double accum; deterministic). sb[c]=g*rstd, sb[128+c]=b-mean*g*rstd.
__global__ __launch_bounds__(256) void bn_stats(
    const float* __restrict__ t, const float* __restrict__ gamma,
    const float* __restrict__ beta, float* __restrict__ sb) {
  int c = blockIdx.x;
  int tid = threadIdx.x;
  double s = 0.0, s2 = 0.0;
  for (int i = tid; i < NIMG * HW * HW; i += 256) {
    int n = i / (HW * HW);
    int rem = i % (HW * HW);
    int r = rem / HW, x = rem % HW;
    float v = t[((size_t)(n * NCH + c) * PADH + r + 1) * PADW + x + 1];
    s += v; s2 += (double)v * v;
  }
  __shared__ double sd[256], sq[256];
  sd[tid] = s; sq[tid] = s2;
  __syncthreads();
  for (int off = 128; off > 0; off >>= 1) {
    if (tid < off) { sd[tid] += sd[tid + off]; sq[tid] += sq[tid + off]; }
    __syncthreads();
  }
  if (tid == 0) {
    double cnt = (double)(NIMG * HW * HW);
    double mean = sd[0] / cnt;
    double var = sq[0] / cnt - mean * mean;
    double rstd = 1.0 / sqrt(var + 1e-5);
    double g = (double)gamma[c];
    sb[c] = (float)(g * rstd);
    sb[NCH + c] = (float)((double)beta[c] - mean * g * rstd);
  }
}

// Final: out = relu(bn2(t5) + residual x), compact NCHW output.
__global__ __launch_bounds__(256) void final_kernel(
    const float* __restrict__ t5, const float* __restrict__ sb,
    const float* __restrict__ x, float* __restrict__ out) {
  int idx = blockIdx.x * 256 + threadIdx.x;          // 802816 float4 threads
  int f = idx * 4;
  int n = f / (NCH * HW * HW);
  int c = (f / (HW * HW)) % NCH;
  int o = f % (HW * HW);
  int y = o / HW, xc = o % HW;
  const float* tp = t5 + ((size_t)(n * NCH + c) * PADH + y + 1) * PADW + xc + 1;
  float sc = sb[c], bi = sb[NCH + c];
  float4 xv = *(const float4*)(x + f);
  float4 ov;
  ov.x = fmaxf(fmaf(tp[0], sc, bi) + xv.x, 0.0f);
  ov.y = fmaxf(fmaf(tp[1], sc, bi) + xv.y, 0.0f);
  ov.z = fmaxf(fmaf(tp[2], sc, bi) + xv.z, 0.0f);
  ov.w = fmaxf(fmaf(tp[3], sc, bi) + xv.w, 0.0f);
  *(float4*)(out + f) = ov;
}

// ---------------------------------------------------------------------------
extern "C" void kernel_launch(void* const* d_in, const int* in_sizes, int n_in,
                              void* d_out, int out_size, void* d_ws, size_t ws_size,
                              hipStream_t stream) {
  const float* x   = (const float*)d_in[0];
  const float* ws1 = (const float*)d_in[1];
  const float* wa1 = (const float*)d_in[2];
  const float* g1  = (const float*)d_in[3];
  const float* b1  = (const float*)d_in[4];
  const float* ws2 = (const float*)d_in[5];
  const float* wa2 = (const float*)d_in[6];
  const float* g2  = (const float*)d_in[7];
  const float* b2  = (const float*)d_in[8];
  float* out = (float*)d_out;

  float* w = (float*)d_ws;
  float* P1 = w;                             // t1 / t4 (fp32 padded)
  float* P2 = w + PBUF;                      // t2 / t5 (fp32 padded)
  unsigned short* CL0 = (unsigned short*)(w + 2 * PBUF);  // x  bf16-cl padded
  unsigned short* CL1 = CL0 + PBUF;                       // t3 bf16-cl padded
  float* WA = w + 3 * PBUF;                  // adder weights fp32 x2
  unsigned short* WS = (unsigned short*)(WA + 2 * (size_t)WREL);  // shift bf16 x2
  float* SB1 = WA + 3 * (size_t)WREL;        // after WS (2*WREL ushorts)
  float* SB2 = SB1 + 256;

  hipLaunchKernelGGL(prep_adder,      dim3(1152), dim3(256), 0, stream, wa1, wa2, WA);
  hipLaunchKernelGGL(prep_shift,      dim3(1152), dim3(256), 0, stream, ws1, ws2, WS);
  hipLaunchKernelGGL(pad_cl,          dim3(960),  dim3(256), 0, stream, x, CL0);
  hipLaunchKernelGGL(zero_halo,       dim3(1920), dim3(256), 0, stream, P1);
  hipLaunchKernelGGL(shift_mfma,      dim3(3136), dim3(256), 0, stream, CL0, WS, P1);            // t1
  hipLaunchKernelGGL(adder_conv,      dim3(784),  dim3(256), 0, stream, P1, WA, P2);             // t2
  hipLaunchKernelGGL(bn_stats,        dim3(128),  dim3(256), 0, stream, P2, g1, b1, SB1);
  hipLaunchKernelGGL(bn_apply_relu_cl,dim3(960),  dim3(256), 0, stream, P2, SB1, CL1);           // t3
  hipLaunchKernelGGL(shift_mfma,      dim3(3136), dim3(256), 0, stream, CL1, WS + WREL, P1);     // t4
  hipLaunchKernelGGL(adder_conv,      dim3(784),  dim3(256), 0, stream, P1, WA + WREL, P2);      // t5
  hipLaunchKernelGGL(bn_stats,        dim3(128),  dim3(256), 0, stream, P2, g2, b2, SB2);
  hipLaunchKernelGGL(final_kernel,    dim3(3136), dim3(256), 0, stream, P2, SB2, x, out);
}

// Round 9
// 672.701 us; speedup vs baseline: 1.5248x; 1.3029x over previous
//
#include <hip/hip_runtime.h>

// Padded fp32 layout for conv tensors: [N][C][30][32], halos zero.
// Channel-last bf16 layout for MFMA inputs: [N][30][32][128] (halos zero).
#define PADH 30
#define PADW 32
#define CSTR (PADH*PADW)            // 960 floats per channel
#define NIMG 32
#define NCH  128
#define HW   28
#define PBUF ((size_t)NIMG*NCH*CSTR)   // 3,932,160
#define WREL (128*128*9)               // 147456 weights per tensor

typedef __attribute__((ext_vector_type(8))) short bf16x8;
typedef __attribute__((ext_vector_type(4))) float f32x4;

__device__ __forceinline__ unsigned short f2bf(float f) {   // RNE
  unsigned u = __float_as_uint(f);
  return (unsigned short)((u + 0x7FFFu + ((u >> 16) & 1u)) >> 16);
}

// ---------------------------------------------------------------------------
// Adder weights -> [cog16][ci(128)][tap(9)][co8] fp32 (LDS-staged layout).
__global__ __launch_bounds__(256) void prep_adder(
    const float* __restrict__ a1, const float* __restrict__ a2,
    float* __restrict__ dst) {
  int gid = blockIdx.x * 256 + threadIdx.x;          // 2*147456 threads
  int t = gid / WREL, r = gid % WREL;
  float v = (t ? a2 : a1)[r];
  int co = r / 1152, rem = r % 1152;
  int ci = rem / 9, tap = rem % 9;
  int cog = co >> 3, j = co & 7;
  dst[(size_t)t * WREL + (((cog * 128 + ci) * 9 + tap) << 3) + j] = v;
}

// Shift weights: quantize sign*2^round(log2|w|) (zero < 0.005), exact in bf16.
// Layout [cog8][tap9][co16][ci128] bf16 so the MFMA A-frag is one b128/lane.
__global__ __launch_bounds__(256) void prep_shift(
    const float* __restrict__ s1, const float* __restrict__ s2,
    unsigned short* __restrict__ dst) {
  int gid = blockIdx.x * 256 + threadIdx.x;          // 2*147456 threads
  int t = gid / WREL, r = gid % WREL;
  float v = (t ? s2 : s1)[r];
  float aw = fabsf(v);
  if (aw < 0.005f) {
    v = 0.0f;
  } else {
    int e; float m = frexpf(aw, &e);
    int k = (m >= 0.70710678f) ? e : e - 1;          // round(log2 aw)
    v = ldexpf(copysignf(1.0f, v), k);               // exact power of two
  }
  int co = r / 1152, rem = r % 1152;
  int ci = rem / 9, tap = rem % 9;
  int cog = co >> 4, cop = co & 15;
  dst[(size_t)t * WREL + (size_t)((cog * 9 + tap) * 16 + cop) * 128 + ci] = f2bf(v);
}

// ---------------------------------------------------------------------------
// x (compact NCHW fp32) -> channel-last bf16 padded [n][yp30][xp32][ci128].
// Block = (n, yp); LDS transpose tile with stride 130 (conflict-free).
__global__ __launch_bounds__(256) void pad_cl(
    const float* __restrict__ x, unsigned short* __restrict__ o) {
  __shared__ unsigned short tile[32 * 130];
  int n = blockIdx.x / PADH, yp = blockIdx.x % PADH;
  int tid = threadIdx.x;
  bool rowok = (yp >= 1 && yp <= HW);
#pragma unroll
  for (int it = 0; it < 16; ++it) {
    int idx = it * 256 + tid;                        // xp fast -> coalesced read
    int ci = idx >> 5, xp = idx & 31;
    float v = 0.0f;
    if (rowok && xp >= 1 && xp <= HW)
      v = x[(size_t)(n * NCH + ci) * (HW * HW) + (yp - 1) * HW + (xp - 1)];
    tile[xp * 130 + ci] = f2bf(v);
  }
  __syncthreads();
  unsigned int* ob = (unsigned int*)(o + (size_t)(n * PADH + yp) * PADW * NCH);
#pragma unroll
  for (int it = 0; it < 8; ++it) {
    int uidx = it * 256 + tid;                       // 2048 uints
    int xp = uidx >> 6, cj = uidx & 63;
    ob[xp * 64 + cj] = *(const unsigned int*)&tile[xp * 130 + 2 * cj];
  }
}

// t2 (fp32 padded) -> BN+ReLU -> channel-last bf16 padded (halos zero).
__global__ __launch_bounds__(256) void bn_apply_relu_cl(
    const float* __restrict__ t, const float* __restrict__ sb,
    unsigned short* __restrict__ o) {
  __shared__ unsigned short tile[32 * 130];
  int n = blockIdx.x / PADH, yp = blockIdx.x % PADH;
  int tid = threadIdx.x;
  bool rowok = (yp >= 1 && yp <= HW);
#pragma unroll
  for (int it = 0; it < 16; ++it) {
    int idx = it * 256 + tid;
    int ci = idx >> 5, xp = idx & 31;
    float v = 0.0f;
    if (rowok && xp >= 1 && xp <= HW) {
      float tv = t[((size_t)(n * NCH + ci) * PADH + yp) * PADW + xp];
      v = fmaxf(fmaf(tv, sb[ci], sb[NCH + ci]), 0.0f);
    }
    tile[xp * 130 + ci] = f2bf(v);
  }
  __syncthreads();
  unsigned int* ob = (unsigned int*)(o + (size_t)(n * PADH + yp) * PADW * NCH);
#pragma unroll
  for (int it = 0; it < 8; ++it) {
    int uidx = it * 256 + tid;
    int xp = uidx >> 6, cj = uidx & 63;
    ob[xp * 64 + cj] = *(const unsigned int*)&tile[xp * 130 + 2 * cj];
  }
}

// Zero halo cells of a padded fp32 buffer (once; convs write interior only).
__global__ __launch_bounds__(256) void zero_halo(float* __restrict__ b) {
  int gid = blockIdx.x * 256 + threadIdx.x;          // 4096*120 threads
  int nc = gid / 120, i = gid % 120;
  float* p = b + (size_t)nc * CSTR;
  if (i < 64) {
    int row = (i < 32) ? 0 : (PADH - 1);
    p[row * PADW + (i & 31)] = 0.0f;
  } else {
    int i2 = i - 64;
    int row = 1 + (i2 >> 1);
    int col = (i2 & 1) ? (HW + 1) : 0;
    p[row * PADW + col] = 0.0f;
  }
}

// ---------------------------------------------------------------------------
// Shift conv on matrix cores. D[co16][px16] = sum_k W[co][k] * In[k][px].
__global__ __launch_bounds__(256) void shift_mfma(
    const unsigned short* __restrict__ in, const unsigned short* __restrict__ wq,
    float* __restrict__ out) {
  int wg = blockIdx.x * 4 + (threadIdx.x >> 6);      // 0..12543
  int lane = threadIdx.x & 63;
  int cot = wg & 7;
  int rem = wg >> 3;                                 // 0..1567
  int pxt = rem % 49;
  int n = rem / 49;
  int px = pxt * 16 + (lane & 15);
  int y = px / HW, x = px % HW;
  int kg = lane >> 4;                                // 0..3

  const unsigned short* ibase =
      in + ((size_t)(n * PADH + y + 1) * PADW + (x + 1)) * NCH + kg * 8;
  const unsigned short* wbase =
      wq + ((size_t)(cot * 9) * 16 + (lane & 15)) * NCH + kg * 8;

  f32x4 acc = {0.f, 0.f, 0.f, 0.f};
#pragma unroll
  for (int tap = 0; tap < 9; ++tap) {
    const int ky = tap / 3 - 1, kx = tap % 3 - 1;
    const unsigned short* ib = ibase + (ky * PADW + kx) * NCH;
    const unsigned short* wb = wbase + (size_t)tap * 16 * NCH;
#pragma unroll
    for (int kc = 0; kc < 4; ++kc) {
      bf16x8 a = *(const bf16x8*)(wb + kc * 32);
      bf16x8 b = *(const bf16x8*)(ib + kc * 32);
      acc = __builtin_amdgcn_mfma_f32_16x16x32_bf16(a, b, acc, 0, 0, 0);
    }
  }
  int coa = cot * 16 + (lane >> 4) * 4;
  float* ob = out + ((size_t)(n * NCH + coa) * PADH + (y + 1)) * PADW + (x + 1);
#pragma unroll
  for (int r = 0; r < 4; ++r) ob[r * CSTR] = acc[r];
}

// ---------------------------------------------------------------------------
// AdderNet conv: out = -sum |in - w|. LDS weight slice 36 KB, 2px x 8co per
// thread, XCD swizzle, 2-deep ci pipeline. The |x-w| op is forced to the
// 2-instr form (v_sub + v_add with |.| source modifier) via register-only
// inline asm -- compiler was emitting an unfused 3-instr sequence (R8 PMC:
// VALU-busy time ~1.9x the 2-instr model).
__device__ __forceinline__ void adder_op(float& acc, float v, float w) {
  float d;
  asm("v_sub_f32 %0, %1, %2" : "=v"(d) : "v"(v), "v"(w));
  asm("v_add_f32 %0, %0, |%1|" : "+v"(acc) : "v"(d));
}

__device__ __forceinline__ void load_rows(const float* __restrict__ p,
                                          float r[3][4]) {
#pragma unroll
  for (int ky = 0; ky < 3; ++ky) {
    float2 a = *(const float2*)(p + ky * PADW);
    float2 b = *(const float2*)(p + ky * PADW + 2);
    r[ky][0] = a.x; r[ky][1] = a.y; r[ky][2] = b.x; r[ky][3] = b.y;
  }
}

__device__ __forceinline__ void adder_ci(const float r[3][4],
                                         const float4* __restrict__ wv,
                                         float acc[8][2]) {
#pragma unroll
  for (int ky = 0; ky < 3; ++ky)
#pragma unroll
    for (int kx = 0; kx < 3; ++kx) {
      float4 wA = wv[(ky * 3 + kx) * 2];
      float4 wB = wv[(ky * 3 + kx) * 2 + 1];
#pragma unroll
      for (int p = 0; p < 2; ++p) {
        float v = r[ky][kx + p];
        adder_op(acc[0][p], v, wA.x);
        adder_op(acc[1][p], v, wA.y);
        adder_op(acc[2][p], v, wA.z);
        adder_op(acc[3][p], v, wA.w);
        adder_op(acc[4][p], v, wB.x);
        adder_op(acc[5][p], v, wB.y);
        adder_op(acc[6][p], v, wB.z);
        adder_op(acc[7][p], v, wB.w);
      }
    }
}

__global__ __launch_bounds__(256, 4) void adder_conv(
    const float* __restrict__ in, const float* __restrict__ wr,
    float* __restrict__ out) {
  __shared__ float4 ws[2304];                        // 128 ci * 18 float4 = 36 KB
  int bid = blockIdx.x;
  int v = (bid & 7) * 98 + (bid >> 3);               // XCD-contiguous remap (784=8*98)
  int cog = v & 15;
  int chunk = v >> 4;                                // 0..48
  int tid = threadIdx.x;
  const float4* src4 = (const float4*)(wr + (size_t)cog * 9216);
#pragma unroll
  for (int k = 0; k < 9; ++k) ws[k * 256 + tid] = src4[k * 256 + tid];
  __syncthreads();

  int wi = chunk * 256 + tid;                        // 0..12543
  int xh = wi % 14;
  int r2 = wi / 14;
  int y = r2 % 28;
  int n = r2 / 28;
  int x0 = xh << 1;
  const float* ib = in + (size_t)n * NCH * CSTR + y * PADW + x0;
  float acc[8][2];
#pragma unroll
  for (int j = 0; j < 8; ++j) { acc[j][0] = 0.0f; acc[j][1] = 0.0f; }

  float ra[3][4], rb[3][4];
  load_rows(ib, ra);
  for (int ci = 0; ci < 128; ci += 2) {
    load_rows(ib + CSTR, rb);
    adder_ci(ra, ws + ci * 18, acc);
    if (ci + 2 < 128) load_rows(ib + 2 * CSTR, ra);
    adder_ci(rb, ws + (ci + 1) * 18, acc);
    ib += 2 * CSTR;
  }

  float* ob = out + ((size_t)(n * NCH + (cog << 3)) * PADH + (y + 1)) * PADW + (x0 + 1);
#pragma unroll
  for (int j = 0; j < 8; ++j) {
    ob[j * CSTR + 0] = -acc[j][0];
    ob[j * CSTR + 1] = -acc[j][1];
  }
}

// ---------------------------------------------------------------------------
// BN batch stats (double accum; deterministic). sb[c]=g*rstd, sb[128+c]=b-mean*g*rstd.
__global__ __launch_bounds__(256) void bn_stats(
    const float* __restrict__ t, const float* __restrict__ gamma,
    const float* __restrict__ beta, float* __restrict__ sb) {
  int c = blockIdx.x;
  int tid = threadIdx.x;
  double s = 0.0, s2 = 0.0;
  for (int i = tid; i < NIMG * HW * HW; i += 256) {
    int n = i / (HW * HW);
    int rem = i % (HW * HW);
    int r = rem / HW, x = rem % HW;
    float v = t[((size_t)(n * NCH + c) * PADH + r + 1) * PADW + x + 1];
    s += v; s2 += (double)v * v;
  }
  __shared__ double sd[256], sq[256];
  sd[tid] = s; sq[tid] = s2;
  __syncthreads();
  for (int off = 128; off > 0; off >>= 1) {
    if (tid < off) { sd[tid] += sd[tid + off]; sq[tid] += sq[tid + off]; }
    __syncthreads();
  }
  if (tid == 0) {
    double cnt = (double)(NIMG * HW * HW);
    double mean = sd[0] / cnt;
    double var = sq[0] / cnt - mean * mean;
    double rstd = 1.0 / sqrt(var + 1e-5);
    double g = (double)gamma[c];
    sb[c] = (float)(g * rstd);
    sb[NCH + c] = (float)((double)beta[c] - mean * g * rstd);
  }
}

// Final: out = relu(bn2(t5) + residual x), compact NCHW output.
__global__ __launch_bounds__(256) void final_kernel(
    const float* __restrict__ t5, const float* __restrict__ sb,
    const float* __restrict__ x, float* __restrict__ out) {
  int idx = blockIdx.x * 256 + threadIdx.x;          // 802816 float4 threads
  int f = idx * 4;
  int n = f / (NCH * HW * HW);
  int c = (f / (HW * HW)) % NCH;
  int o = f % (HW * HW);
  int y = o / HW, xc = o % HW;
  const float* tp = t5 + ((size_t)(n * NCH + c) * PADH + y + 1) * PADW + xc + 1;
  float sc = sb[c], bi = sb[NCH + c];
  float4 xv = *(const float4*)(x + f);
  float4 ov;
  ov.x = fmaxf(fmaf(tp[0], sc, bi) + xv.x, 0.0f);
  ov.y = fmaxf(fmaf(tp[1], sc, bi) + xv.y, 0.0f);
  ov.z = fmaxf(fmaf(tp[2], sc, bi) + xv.z, 0.0f);
  ov.w = fmaxf(fmaf(tp[3], sc, bi) + xv.w, 0.0f);
  *(float4*)(out + f) = ov;
}

// ---------------------------------------------------------------------------
extern "C" void kernel_launch(void* const* d_in, const int* in_sizes, int n_in,
                              void* d_out, int out_size, void* d_ws, size_t ws_size,
                              hipStream_t stream) {
  const float* x   = (const float*)d_in[0];
  const float* ws1 = (const float*)d_in[1];
  const float* wa1 = (const float*)d_in[2];
  const float* g1  = (const float*)d_in[3];
  const float* b1  = (const float*)d_in[4];
  const float* ws2 = (const float*)d_in[5];
  const float* wa2 = (const float*)d_in[6];
  const float* g2  = (const float*)d_in[7];
  const float* b2  = (const float*)d_in[8];
  float* out = (float*)d_out;

  float* w = (float*)d_ws;
  float* P1 = w;                             // t1 / t4 (fp32 padded)
  float* P2 = w + PBUF;                      // t2 / t5 (fp32 padded)
  unsigned short* CL0 = (unsigned short*)(w + 2 * PBUF);  // x  bf16-cl padded
  unsigned short* CL1 = CL0 + PBUF;                       // t3 bf16-cl padded
  float* WA = w + 3 * PBUF;                  // adder weights fp32 x2
  unsigned short* WS = (unsigned short*)(WA + 2 * (size_t)WREL);  // shift bf16 x2
  float* SB1 = WA + 3 * (size_t)WREL;        // after WS (2*WREL ushorts)
  float* SB2 = SB1 + 256;

  hipLaunchKernelGGL(prep_adder,      dim3(1152), dim3(256), 0, stream, wa1, wa2, WA);
  hipLaunchKernelGGL(prep_shift,      dim3(1152), dim3(256), 0, stream, ws1, ws2, WS);
  hipLaunchKernelGGL(pad_cl,          dim3(960),  dim3(256), 0, stream, x, CL0);
  hipLaunchKernelGGL(zero_halo,       dim3(1920), dim3(256), 0, stream, P1);
  hipLaunchKernelGGL(shift_mfma,      dim3(3136), dim3(256), 0, stream, CL0, WS, P1);            // t1
  hipLaunchKernelGGL(adder_conv,      dim3(784),  dim3(256), 0, stream, P1, WA, P2);             // t2
  hipLaunchKernelGGL(bn_stats,        dim3(128),  dim3(256), 0, stream, P2, g1, b1, SB1);
  hipLaunchKernelGGL(bn_apply_relu_cl,dim3(960),  dim3(256), 0, stream, P2, SB1, CL1);           // t3
  hipLaunchKernelGGL(shift_mfma,      dim3(3136), dim3(256), 0, stream, CL1, WS + WREL, P1);     // t4
  hipLaunchKernelGGL(adder_conv,      dim3(784),  dim3(256), 0, stream, P1, WA + WREL, P2);      // t5
  hipLaunchKernelGGL(bn_stats,        dim3(128),  dim3(256), 0, stream, P2, g2, b2, SB2);
  hipLaunchKernelGGL(final_kernel,    dim3(3136), dim3(256), 0, stream, P2, SB2, x, out);
}

// Round 10
// 640.491 us; speedup vs baseline: 1.6014x; 1.0503x over previous
//
#include <hip/hip_runtime.h>

// Padded layouts (halos zero):
//   fp32 [N][C][30][32]  : adder OUTPUTS (t2/t5)
//   u32  [N][C][30][32]  : adder INPUTS (t1/t4), fixed-point q = rn((v+16)*2^16)
//   bf16 [N][30][32][128]: MFMA inputs (x, t3) channel-last
#define PADH 30
#define PADW 32
#define CSTR (PADH*PADW)            // 960 elems per channel
#define NIMG 32
#define NCH  128
#define HW   28
#define PBUF ((size_t)NIMG*NCH*CSTR)   // 3,932,160
#define WREL (128*128*9)               // 147456 weights per tensor

#define QSCALE 65536.0f
#define QINV  (-1.52587890625e-05f)    // -1/65536 (adder output is negated sum)
#define QZERO 1048576u                 // rn((0+16)*65536)

typedef __attribute__((ext_vector_type(8))) short bf16x8;
typedef __attribute__((ext_vector_type(4))) float f32x4;

__device__ __forceinline__ unsigned short f2bf(float f) {   // RNE
  unsigned u = __float_as_uint(f);
  return (unsigned short)((u + 0x7FFFu + ((u >> 16) & 1u)) >> 16);
}

// ---------------------------------------------------------------------------
// Adder weights -> [cog16][ci(128)][tap(9)][co8] u32 fixed-point.
__global__ __launch_bounds__(256) void prep_adder(
    const float* __restrict__ a1, const float* __restrict__ a2,
    unsigned* __restrict__ dst) {
  int gid = blockIdx.x * 256 + threadIdx.x;          // 2*147456 threads
  int t = gid / WREL, r = gid % WREL;
  float v = (t ? a2 : a1)[r];
  unsigned q = __float2uint_rn((v + 16.0f) * QSCALE);
  int co = r / 1152, rem = r % 1152;
  int ci = rem / 9, tap = rem % 9;
  int cog = co >> 3, j = co & 7;
  dst[(size_t)t * WREL + (((cog * 128 + ci) * 9 + tap) << 3) + j] = q;
}

// Shift weights: quantize sign*2^round(log2|w|) (zero < 0.005), exact in bf16.
// Layout [cog8][tap9][co16][ci128] bf16 so the MFMA A-frag is one b128/lane.
__global__ __launch_bounds__(256) void prep_shift(
    const float* __restrict__ s1, const float* __restrict__ s2,
    unsigned short* __restrict__ dst) {
  int gid = blockIdx.x * 256 + threadIdx.x;          // 2*147456 threads
  int t = gid / WREL, r = gid % WREL;
  float v = (t ? s2 : s1)[r];
  float aw = fabsf(v);
  if (aw < 0.005f) {
    v = 0.0f;
  } else {
    int e; float m = frexpf(aw, &e);
    int k = (m >= 0.70710678f) ? e : e - 1;          // round(log2 aw)
    v = ldexpf(copysignf(1.0f, v), k);               // exact power of two
  }
  int co = r / 1152, rem = r % 1152;
  int ci = rem / 9, tap = rem % 9;
  int cog = co >> 4, cop = co & 15;
  dst[(size_t)t * WREL + (size_t)((cog * 9 + tap) * 16 + cop) * 128 + ci] = f2bf(v);
}

// ---------------------------------------------------------------------------
// x (compact NCHW fp32) -> channel-last bf16 padded [n][yp30][xp32][ci128].
__global__ __launch_bounds__(256) void pad_cl(
    const float* __restrict__ x, unsigned short* __restrict__ o) {
  __shared__ unsigned short tile[32 * 130];
  int n = blockIdx.x / PADH, yp = blockIdx.x % PADH;
  int tid = threadIdx.x;
  bool rowok = (yp >= 1 && yp <= HW);
#pragma unroll
  for (int it = 0; it < 16; ++it) {
    int idx = it * 256 + tid;                        // xp fast -> coalesced read
    int ci = idx >> 5, xp = idx & 31;
    float v = 0.0f;
    if (rowok && xp >= 1 && xp <= HW)
      v = x[(size_t)(n * NCH + ci) * (HW * HW) + (yp - 1) * HW + (xp - 1)];
    tile[xp * 130 + ci] = f2bf(v);
  }
  __syncthreads();
  unsigned int* ob = (unsigned int*)(o + (size_t)(n * PADH + yp) * PADW * NCH);
#pragma unroll
  for (int it = 0; it < 8; ++it) {
    int uidx = it * 256 + tid;                       // 2048 uints
    int xp = uidx >> 6, cj = uidx & 63;
    ob[xp * 64 + cj] = *(const unsigned int*)&tile[xp * 130 + 2 * cj];
  }
}

// t2 (fp32 padded) -> BN+ReLU -> channel-last bf16 padded (halos zero).
__global__ __launch_bounds__(256) void bn_apply_relu_cl(
    const float* __restrict__ t, const float* __restrict__ sb,
    unsigned short* __restrict__ o) {
  __shared__ unsigned short tile[32 * 130];
  int n = blockIdx.x / PADH, yp = blockIdx.x % PADH;
  int tid = threadIdx.x;
  bool rowok = (yp >= 1 && yp <= HW);
#pragma unroll
  for (int it = 0; it < 16; ++it) {
    int idx = it * 256 + tid;
    int ci = idx >> 5, xp = idx & 31;
    float v = 0.0f;
    if (rowok && xp >= 1 && xp <= HW) {
      float tv = t[((size_t)(n * NCH + ci) * PADH + yp) * PADW + xp];
      v = fmaxf(fmaf(tv, sb[ci], sb[NCH + ci]), 0.0f);
    }
    tile[xp * 130 + ci] = f2bf(v);
  }
  __syncthreads();
  unsigned int* ob = (unsigned int*)(o + (size_t)(n * PADH + yp) * PADW * NCH);
#pragma unroll
  for (int it = 0; it < 8; ++it) {
    int uidx = it * 256 + tid;
    int xp = uidx >> 6, cj = uidx & 63;
    ob[xp * 64 + cj] = *(const unsigned int*)&tile[xp * 130 + 2 * cj];
  }
}

// Zero (quantized) halo cells of the u32 adder-input buffer.
__global__ __launch_bounds__(256) void zero_halo(unsigned* __restrict__ b) {
  int gid = blockIdx.x * 256 + threadIdx.x;          // 4096*120 threads
  int nc = gid / 120, i = gid % 120;
  unsigned* p = b + (size_t)nc * CSTR;
  if (i < 64) {
    int row = (i < 32) ? 0 : (PADH - 1);
    p[row * PADW + (i & 31)] = QZERO;
  } else {
    int i2 = i - 64;
    int row = 1 + (i2 >> 1);
    int col = (i2 & 1) ? (HW + 1) : 0;
    p[row * PADW + col] = QZERO;
  }
}

// ---------------------------------------------------------------------------
// Shift conv on matrix cores; epilogue emits u32 fixed-point for the adder.
__global__ __launch_bounds__(256) void shift_mfma(
    const unsigned short* __restrict__ in, const unsigned short* __restrict__ wq,
    unsigned* __restrict__ out) {
  int wg = blockIdx.x * 4 + (threadIdx.x >> 6);      // 0..12543
  int lane = threadIdx.x & 63;
  int cot = wg & 7;
  int rem = wg >> 3;                                 // 0..1567
  int pxt = rem % 49;
  int n = rem / 49;
  int px = pxt * 16 + (lane & 15);
  int y = px / HW, x = px % HW;
  int kg = lane >> 4;                                // 0..3

  const unsigned short* ibase =
      in + ((size_t)(n * PADH + y + 1) * PADW + (x + 1)) * NCH + kg * 8;
  const unsigned short* wbase =
      wq + ((size_t)(cot * 9) * 16 + (lane & 15)) * NCH + kg * 8;

  f32x4 acc = {0.f, 0.f, 0.f, 0.f};
#pragma unroll
  for (int tap = 0; tap < 9; ++tap) {
    const int ky = tap / 3 - 1, kx = tap % 3 - 1;
    const unsigned short* ib = ibase + (ky * PADW + kx) * NCH;
    const unsigned short* wb = wbase + (size_t)tap * 16 * NCH;
#pragma unroll
    for (int kc = 0; kc < 4; ++kc) {
      bf16x8 a = *(const bf16x8*)(wb + kc * 32);
      bf16x8 b = *(const bf16x8*)(ib + kc * 32);
      acc = __builtin_amdgcn_mfma_f32_16x16x32_bf16(a, b, acc, 0, 0, 0);
    }
  }
  int coa = cot * 16 + (lane >> 4) * 4;
  unsigned* ob = out + ((size_t)(n * NCH + coa) * PADH + (y + 1)) * PADW + (x + 1);
#pragma unroll
  for (int r = 0; r < 4; ++r) {
    float v = fminf(fmaxf(acc[r], -15.9f), 15.9f);   // 16-sigma clamp, unreachable
    ob[r * CSTR] = __float2uint_rn((v + 16.0f) * QSCALE);
  }
}

// ---------------------------------------------------------------------------
// AdderNet conv, integer SAD form: acc = v_sad_u32(a, b, acc) = |a-b| + acc,
// ONE full-rate VALU instr per term (R9: VALUBusy 99% -> instr count is the
// limit; this halves it vs v_sub+v_add|.|).
__device__ __forceinline__ void sad_op(unsigned& acc, unsigned a, unsigned b) {
  asm("v_sad_u32 %0, %1, %2, %0" : "+v"(acc) : "v"(a), "v"(b));
}

__device__ __forceinline__ void load_rows_u(const unsigned* __restrict__ p,
                                            unsigned r[3][4]) {
#pragma unroll
  for (int ky = 0; ky < 3; ++ky) {
    uint2 a = *(const uint2*)(p + ky * PADW);
    uint2 b = *(const uint2*)(p + ky * PADW + 2);
    r[ky][0] = a.x; r[ky][1] = a.y; r[ky][2] = b.x; r[ky][3] = b.y;
  }
}

__device__ __forceinline__ void adder_ci(const unsigned r[3][4],
                                         const uint4* __restrict__ wv,
                                         unsigned acc[8][2]) {
#pragma unroll
  for (int ky = 0; ky < 3; ++ky)
#pragma unroll
    for (int kx = 0; kx < 3; ++kx) {
      uint4 wA = wv[(ky * 3 + kx) * 2];
      uint4 wB = wv[(ky * 3 + kx) * 2 + 1];
#pragma unroll
      for (int p = 0; p < 2; ++p) {
        unsigned v = r[ky][kx + p];
        sad_op(acc[0][p], v, wA.x);
        sad_op(acc[1][p], v, wA.y);
        sad_op(acc[2][p], v, wA.z);
        sad_op(acc[3][p], v, wA.w);
        sad_op(acc[4][p], v, wB.x);
        sad_op(acc[5][p], v, wB.y);
        sad_op(acc[6][p], v, wB.z);
        sad_op(acc[7][p], v, wB.w);
      }
    }
}

__global__ __launch_bounds__(256, 4) void adder_conv(
    const unsigned* __restrict__ in, const unsigned* __restrict__ wr,
    float* __restrict__ out) {
  __shared__ uint4 ws[2304];                         // 128 ci * 18 uint4 = 36 KB
  int bid = blockIdx.x;
  int v = (bid & 7) * 98 + (bid >> 3);               // XCD-contiguous remap (784=8*98)
  int cog = v & 15;
  int chunk = v >> 4;                                // 0..48
  int tid = threadIdx.x;
  const uint4* src4 = (const uint4*)(wr + (size_t)cog * 9216);
#pragma unroll
  for (int k = 0; k < 9; ++k) ws[k * 256 + tid] = src4[k * 256 + tid];
  __syncthreads();

  int wi = chunk * 256 + tid;                        // 0..12543
  int xh = wi % 14;
  int r2 = wi / 14;
  int y = r2 % 28;
  int n = r2 / 28;
  int x0 = xh << 1;
  const unsigned* ib = in + (size_t)n * NCH * CSTR + y * PADW + x0;
  unsigned acc[8][2];
#pragma unroll
  for (int j = 0; j < 8; ++j) { acc[j][0] = 0u; acc[j][1] = 0u; }

  unsigned ra[3][4], rb[3][4];
  load_rows_u(ib, ra);
  for (int ci = 0; ci < 128; ci += 2) {
    load_rows_u(ib + CSTR, rb);
    adder_ci(ra, ws + ci * 18, acc);
    if (ci + 2 < 128) load_rows_u(ib + 2 * CSTR, ra);
    adder_ci(rb, ws + (ci + 1) * 18, acc);
    ib += 2 * CSTR;
  }

  float* ob = out + ((size_t)(n * NCH + (cog << 3)) * PADH + (y + 1)) * PADW + (x0 + 1);
#pragma unroll
  for (int j = 0; j < 8; ++j) {
    ob[j * CSTR + 0] = (float)acc[j][0] * QINV;      // -sum|v-w|
    ob[j * CSTR + 1] = (float)acc[j][1] * QINV;
  }
}

// ---------------------------------------------------------------------------
// BN batch stats (double accum; deterministic). sb[c]=g*rstd, sb[128+c]=b-mean*g*rstd.
__global__ __launch_bounds__(256) void bn_stats(
    const float* __restrict__ t, const float* __restrict__ gamma,
    const float* __restrict__ beta, float* __restrict__ sb) {
  int c = blockIdx.x;
  int tid = threadIdx.x;
  double s = 0.0, s2 = 0.0;
  for (int i = tid; i < NIMG * HW * HW; i += 256) {
    int n = i / (HW * HW);
    int rem = i % (HW * HW);
    int r = rem / HW, x = rem % HW;
    float v = t[((size_t)(n * NCH + c) * PADH + r + 1) * PADW + x + 1];
    s += v; s2 += (double)v * v;
  }
  __shared__ double sd[256], sq[256];
  sd[tid] = s; sq[tid] = s2;
  __syncthreads();
  for (int off = 128; off > 0; off >>= 1) {
    if (tid < off) { sd[tid] += sd[tid + off]; sq[tid] += sq[tid + off]; }
    __syncthreads();
  }
  if (tid == 0) {
    double cnt = (double)(NIMG * HW * HW);
    double mean = sd[0] / cnt;
    double var = sq[0] / cnt - mean * mean;
    double rstd = 1.0 / sqrt(var + 1e-5);
    double g = (double)gamma[c];
    sb[c] = (float)(g * rstd);
    sb[NCH + c] = (float)((double)beta[c] - mean * g * rstd);
  }
}

// Final: out = relu(bn2(t5) + residual x), compact NCHW output.
__global__ __launch_bounds__(256) void final_kernel(
    const float* __restrict__ t5, const float* __restrict__ sb,
    const float* __restrict__ x, float* __restrict__ out) {
  int idx = blockIdx.x * 256 + threadIdx.x;          // 802816 float4 threads
  int f = idx * 4;
  int n = f / (NCH * HW * HW);
  int c = (f / (HW * HW)) % NCH;
  int o = f % (HW * HW);
  int y = o / HW, xc = o % HW;
  const float* tp = t5 + ((size_t)(n * NCH + c) * PADH + y + 1) * PADW + xc + 1;
  float sc = sb[c], bi = sb[NCH + c];
  float4 xv = *(const float4*)(x + f);
  float4 ov;
  ov.x = fmaxf(fmaf(tp[0], sc, bi) + xv.x, 0.0f);
  ov.y = fmaxf(fmaf(tp[1], sc, bi) + xv.y, 0.0f);
  ov.z = fmaxf(fmaf(tp[2], sc, bi) + xv.z, 0.0f);
  ov.w = fmaxf(fmaf(tp[3], sc, bi) + xv.w, 0.0f);
  *(float4*)(out + f) = ov;
}

// ---------------------------------------------------------------------------
extern "C" void kernel_launch(void* const* d_in, const int* in_sizes, int n_in,
                              void* d_out, int out_size, void* d_ws, size_t ws_size,
                              hipStream_t stream) {
  const float* x   = (const float*)d_in[0];
  const float* ws1 = (const float*)d_in[1];
  const float* wa1 = (const float*)d_in[2];
  const float* g1  = (const float*)d_in[3];
  const float* b1  = (const float*)d_in[4];
  const float* ws2 = (const float*)d_in[5];
  const float* wa2 = (const float*)d_in[6];
  const float* g2  = (const float*)d_in[7];
  const float* b2  = (const float*)d_in[8];
  float* out = (float*)d_out;

  float* w = (float*)d_ws;
  unsigned* P1 = (unsigned*)w;               // t1 / t4 (u32 fixed-point padded)
  float* P2 = w + PBUF;                      // t2 / t5 (fp32 padded)
  unsigned short* CL0 = (unsigned short*)(w + 2 * PBUF);  // x  bf16-cl padded
  unsigned short* CL1 = CL0 + PBUF;                       // t3 bf16-cl padded
  float* WAf = w + 3 * PBUF;                 // adder weights u32 x2 (same size)
  unsigned* WA = (unsigned*)WAf;
  unsigned short* WS = (unsigned short*)(WAf + 2 * (size_t)WREL);  // shift bf16 x2
  float* SB1 = WAf + 3 * (size_t)WREL;       // after WS (2*WREL ushorts)
  float* SB2 = SB1 + 256;

  hipLaunchKernelGGL(prep_adder,      dim3(1152), dim3(256), 0, stream, wa1, wa2, WA);
  hipLaunchKernelGGL(prep_shift,      dim3(1152), dim3(256), 0, stream, ws1, ws2, WS);
  hipLaunchKernelGGL(pad_cl,          dim3(960),  dim3(256), 0, stream, x, CL0);
  hipLaunchKernelGGL(zero_halo,       dim3(1920), dim3(256), 0, stream, P1);
  hipLaunchKernelGGL(shift_mfma,      dim3(3136), dim3(256), 0, stream, CL0, WS, P1);            // t1
  hipLaunchKernelGGL(adder_conv,      dim3(784),  dim3(256), 0, stream, P1, WA, P2);             // t2
  hipLaunchKernelGGL(bn_stats,        dim3(128),  dim3(256), 0, stream, P2, g1, b1, SB1);
  hipLaunchKernelGGL(bn_apply_relu_cl,dim3(960),  dim3(256), 0, stream, P2, SB1, CL1);           // t3
  hipLaunchKernelGGL(shift_mfma,      dim3(3136), dim3(256), 0, stream, CL1, WS + WREL, P1);     // t4
  hipLaunchKernelGGL(adder_conv,      dim3(784),  dim3(256), 0, stream, P1, WA + WREL, P2);      // t5
  hipLaunchKernelGGL(bn_stats,        dim3(128),  dim3(256), 0, stream, P2, g2, b2, SB2);
  hipLaunchKernelGGL(final_kernel,    dim3(3136), dim3(256), 0, stream, P2, SB2, x, out);
}

// Round 11
// 640.460 us; speedup vs baseline: 1.6015x; 1.0000x over previous
//
#include <hip/hip_runtime.h>

// Padded layouts (halos zero):
//   fp32 [N][C][30][32]  : adder OUTPUTS (t2/t5)
//   u32  [N][C][30][32]  : adder INPUTS (t1/t4), fixed-point q = rn((v+16)*2^16)
//   bf16 [N][30][32][128]: MFMA inputs (x, t3) channel-last
#define PADH 30
#define PADW 32
#define CSTR (PADH*PADW)            // 960 elems per channel
#define NIMG 32
#define NCH  128
#define HW   28
#define PBUF ((size_t)NIMG*NCH*CSTR)   // 3,932,160
#define WREL (128*128*9)               // 147456 weights per tensor

#define QSCALE 65536.0f
#define QINV  (-1.52587890625e-05f)    // -1/65536 (adder output is negated sum)
#define QZERO 1048576u                 // rn((0+16)*65536)

typedef __attribute__((ext_vector_type(8))) short bf16x8;
typedef __attribute__((ext_vector_type(4))) float f32x4;
typedef __attribute__((ext_vector_type(4))) unsigned u32x4;
// Constant-address-space view: block-uniform address -> compiler emits s_load
// into SGPRs (scalar pipe), not VMEM/LDS. Proven pattern (R7 passed with it).
typedef __attribute__((address_space(4))) const u32x4 cu32x4;

__device__ __forceinline__ unsigned short f2bf(float f) {   // RNE
  unsigned u = __float_as_uint(f);
  return (unsigned short)((u + 0x7FFFu + ((u >> 16) & 1u)) >> 16);
}

// ---------------------------------------------------------------------------
// Adder weights -> [cog16][ci(128)][tap(9)][co8] u32 fixed-point.
__global__ __launch_bounds__(256) void prep_adder(
    const float* __restrict__ a1, const float* __restrict__ a2,
    unsigned* __restrict__ dst) {
  int gid = blockIdx.x * 256 + threadIdx.x;          // 2*147456 threads
  int t = gid / WREL, r = gid % WREL;
  float v = (t ? a2 : a1)[r];
  unsigned q = __float2uint_rn((v + 16.0f) * QSCALE);
  int co = r / 1152, rem = r % 1152;
  int ci = rem / 9, tap = rem % 9;
  int cog = co >> 3, j = co & 7;
  dst[(size_t)t * WREL + (((cog * 128 + ci) * 9 + tap) << 3) + j] = q;
}

// Shift weights: quantize sign*2^round(log2|w|) (zero < 0.005), exact in bf16.
// Layout [cog8][tap9][co16][ci128] bf16 so the MFMA A-frag is one b128/lane.
__global__ __launch_bounds__(256) void prep_shift(
    const float* __restrict__ s1, const float* __restrict__ s2,
    unsigned short* __restrict__ dst) {
  int gid = blockIdx.x * 256 + threadIdx.x;          // 2*147456 threads
  int t = gid / WREL, r = gid % WREL;
  float v = (t ? s2 : s1)[r];
  float aw = fabsf(v);
  if (aw < 0.005f) {
    v = 0.0f;
  } else {
    int e; float m = frexpf(aw, &e);
    int k = (m >= 0.70710678f) ? e : e - 1;          // round(log2 aw)
    v = ldexpf(copysignf(1.0f, v), k);               // exact power of two
  }
  int co = r / 1152, rem = r % 1152;
  int ci = rem / 9, tap = rem % 9;
  int cog = co >> 4, cop = co & 15;
  dst[(size_t)t * WREL + (size_t)((cog * 9 + tap) * 16 + cop) * 128 + ci] = f2bf(v);
}

// ---------------------------------------------------------------------------
// x (compact NCHW fp32) -> channel-last bf16 padded [n][yp30][xp32][ci128].
__global__ __launch_bounds__(256) void pad_cl(
    const float* __restrict__ x, unsigned short* __restrict__ o) {
  __shared__ unsigned short tile[32 * 130];
  int n = blockIdx.x / PADH, yp = blockIdx.x % PADH;
  int tid = threadIdx.x;
  bool rowok = (yp >= 1 && yp <= HW);
#pragma unroll
  for (int it = 0; it < 16; ++it) {
    int idx = it * 256 + tid;                        // xp fast -> coalesced read
    int ci = idx >> 5, xp = idx & 31;
    float v = 0.0f;
    if (rowok && xp >= 1 && xp <= HW)
      v = x[(size_t)(n * NCH + ci) * (HW * HW) + (yp - 1) * HW + (xp - 1)];
    tile[xp * 130 + ci] = f2bf(v);
  }
  __syncthreads();
  unsigned int* ob = (unsigned int*)(o + (size_t)(n * PADH + yp) * PADW * NCH);
#pragma unroll
  for (int it = 0; it < 8; ++it) {
    int uidx = it * 256 + tid;                       // 2048 uints
    int xp = uidx >> 6, cj = uidx & 63;
    ob[xp * 64 + cj] = *(const unsigned int*)&tile[xp * 130 + 2 * cj];
  }
}

// t2 (fp32 padded) -> BN+ReLU -> channel-last bf16 padded (halos zero).
__global__ __launch_bounds__(256) void bn_apply_relu_cl(
    const float* __restrict__ t, const float* __restrict__ sb,
    unsigned short* __restrict__ o) {
  __shared__ unsigned short tile[32 * 130];
  int n = blockIdx.x / PADH, yp = blockIdx.x % PADH;
  int tid = threadIdx.x;
  bool rowok = (yp >= 1 && yp <= HW);
#pragma unroll
  for (int it = 0; it < 16; ++it) {
    int idx = it * 256 + tid;
    int ci = idx >> 5, xp = idx & 31;
    float v = 0.0f;
    if (rowok && xp >= 1 && xp <= HW) {
      float tv = t[((size_t)(n * NCH + ci) * PADH + yp) * PADW + xp];
      v = fmaxf(fmaf(tv, sb[ci], sb[NCH + ci]), 0.0f);
    }
    tile[xp * 130 + ci] = f2bf(v);
  }
  __syncthreads();
  unsigned int* ob = (unsigned int*)(o + (size_t)(n * PADH + yp) * PADW * NCH);
#pragma unroll
  for (int it = 0; it < 8; ++it) {
    int uidx = it * 256 + tid;
    int xp = uidx >> 6, cj = uidx & 63;
    ob[xp * 64 + cj] = *(const unsigned int*)&tile[xp * 130 + 2 * cj];
  }
}

// Zero (quantized) halo cells of the u32 adder-input buffer.
__global__ __launch_bounds__(256) void zero_halo(unsigned* __restrict__ b) {
  int gid = blockIdx.x * 256 + threadIdx.x;          // 4096*120 threads
  int nc = gid / 120, i = gid % 120;
  unsigned* p = b + (size_t)nc * CSTR;
  if (i < 64) {
    int row = (i < 32) ? 0 : (PADH - 1);
    p[row * PADW + (i & 31)] = QZERO;
  } else {
    int i2 = i - 64;
    int row = 1 + (i2 >> 1);
    int col = (i2 & 1) ? (HW + 1) : 0;
    p[row * PADW + col] = QZERO;
  }
}

// ---------------------------------------------------------------------------
// Shift conv on matrix cores; epilogue emits u32 fixed-point for the adder.
__global__ __launch_bounds__(256) void shift_mfma(
    const unsigned short* __restrict__ in, const unsigned short* __restrict__ wq,
    unsigned* __restrict__ out) {
  int wg = blockIdx.x * 4 + (threadIdx.x >> 6);      // 0..12543
  int lane = threadIdx.x & 63;
  int cot = wg & 7;
  int rem = wg >> 3;                                 // 0..1567
  int pxt = rem % 49;
  int n = rem / 49;
  int px = pxt * 16 + (lane & 15);
  int y = px / HW, x = px % HW;
  int kg = lane >> 4;                                // 0..3

  const unsigned short* ibase =
      in + ((size_t)(n * PADH + y + 1) * PADW + (x + 1)) * NCH + kg * 8;
  const unsigned short* wbase =
      wq + ((size_t)(cot * 9) * 16 + (lane & 15)) * NCH + kg * 8;

  f32x4 acc = {0.f, 0.f, 0.f, 0.f};
#pragma unroll
  for (int tap = 0; tap < 9; ++tap) {
    const int ky = tap / 3 - 1, kx = tap % 3 - 1;
    const unsigned short* ib = ibase + (ky * PADW + kx) * NCH;
    const unsigned short* wb = wbase + (size_t)tap * 16 * NCH;
#pragma unroll
    for (int kc = 0; kc < 4; ++kc) {
      bf16x8 a = *(const bf16x8*)(wb + kc * 32);
      bf16x8 b = *(const bf16x8*)(ib + kc * 32);
      acc = __builtin_amdgcn_mfma_f32_16x16x32_bf16(a, b, acc, 0, 0, 0);
    }
  }
  int coa = cot * 16 + (lane >> 4) * 4;
  unsigned* ob = out + ((size_t)(n * NCH + coa) * PADH + (y + 1)) * PADW + (x + 1);
#pragma unroll
  for (int r = 0; r < 4; ++r) {
    float v = fminf(fmaxf(acc[r], -15.9f), 15.9f);   // 16-sigma clamp, unreachable
    ob[r * CSTR] = __float2uint_rn((v + 16.0f) * QSCALE);
  }
}

// ---------------------------------------------------------------------------
// AdderNet conv, integer SAD with SGPR weights: v_sad_u32 vacc, vin, s_w, vacc
// (VOP3 allows one SGPR source). Weights come from the constant-AS path ->
// scalar pipe; NO LDS in the kernel (R10 PMC: LDS broadcast pipe was the
// limiter at VALUBusy 55%).
__device__ __forceinline__ void sad_op(unsigned& acc, unsigned vin, unsigned w) {
  asm("v_sad_u32 %0, %1, %2, %0" : "+v"(acc) : "v"(vin), "s"(w));
}

__device__ __forceinline__ void load_rows_u(const unsigned* __restrict__ p,
                                            unsigned r[3][4]) {
#pragma unroll
  for (int ky = 0; ky < 3; ++ky) {
    uint2 a = *(const uint2*)(p + ky * PADW);
    uint2 b = *(const uint2*)(p + ky * PADW + 2);
    r[ky][0] = a.x; r[ky][1] = a.y; r[ky][2] = b.x; r[ky][3] = b.y;
  }
}

__device__ __forceinline__ void adder_ci(const unsigned r[3][4],
                                         cu32x4* __restrict__ wv,
                                         unsigned acc[8][2]) {
#pragma unroll
  for (int ky = 0; ky < 3; ++ky)
#pragma unroll
    for (int kx = 0; kx < 3; ++kx) {
      u32x4 wA = wv[(ky * 3 + kx) * 2];              // SGPRs (s_load)
      u32x4 wB = wv[(ky * 3 + kx) * 2 + 1];
#pragma unroll
      for (int p = 0; p < 2; ++p) {
        unsigned v = r[ky][kx + p];
        sad_op(acc[0][p], v, wA.x);
        sad_op(acc[1][p], v, wA.y);
        sad_op(acc[2][p], v, wA.z);
        sad_op(acc[3][p], v, wA.w);
        sad_op(acc[4][p], v, wB.x);
        sad_op(acc[5][p], v, wB.y);
        sad_op(acc[6][p], v, wB.z);
        sad_op(acc[7][p], v, wB.w);
      }
    }
}

__global__ __launch_bounds__(256) void adder_conv(
    const unsigned* __restrict__ in, const unsigned* __restrict__ wr,
    float* __restrict__ out) {
  int bid = blockIdx.x;
  int v = (bid & 7) * 98 + (bid >> 3);               // XCD-contiguous remap (784=8*98)
  int cog = v & 15;
  int chunk = v >> 4;                                // 0..48
  int tid = threadIdx.x;

  int wi = chunk * 256 + tid;                        // 0..12543
  int xh = wi % 14;
  int r2 = wi / 14;
  int y = r2 % 28;
  int n = r2 / 28;
  int x0 = xh << 1;
  const unsigned* ib = in + (size_t)n * NCH * CSTR + y * PADW + x0;
  cu32x4* w4 = (cu32x4*)(wr + (size_t)cog * 9216);   // [ci][18 x u32x4]

  unsigned acc[8][2];
#pragma unroll
  for (int j = 0; j < 8; ++j) { acc[j][0] = 0u; acc[j][1] = 0u; }

  unsigned ra[3][4], rb[3][4];
  load_rows_u(ib, ra);
  for (int ci = 0; ci < 128; ci += 2) {
    load_rows_u(ib + CSTR, rb);
    adder_ci(ra, w4 + (size_t)ci * 18, acc);
    if (ci + 2 < 128) load_rows_u(ib + 2 * CSTR, ra);
    adder_ci(rb, w4 + (size_t)(ci + 1) * 18, acc);
    ib += 2 * CSTR;
  }

  float* ob = out + ((size_t)(n * NCH + (cog << 3)) * PADH + (y + 1)) * PADW + (x0 + 1);
#pragma unroll
  for (int j = 0; j < 8; ++j) {
    ob[j * CSTR + 0] = (float)acc[j][0] * QINV;      // -sum|v-w|
    ob[j * CSTR + 1] = (float)acc[j][1] * QINV;
  }
}

// ---------------------------------------------------------------------------
// BN batch stats (double accum; deterministic). sb[c]=g*rstd, sb[128+c]=b-mean*g*rstd.
__global__ __launch_bounds__(256) void bn_stats(
    const float* __restrict__ t, const float* __restrict__ gamma,
    const float* __restrict__ beta, float* __restrict__ sb) {
  int c = blockIdx.x;
  int tid = threadIdx.x;
  double s = 0.0, s2 = 0.0;
  for (int i = tid; i < NIMG * HW * HW; i += 256) {
    int n = i / (HW * HW);
    int rem = i % (HW * HW);
    int r = rem / HW, x = rem % HW;
    float v = t[((size_t)(n * NCH + c) * PADH + r + 1) * PADW + x + 1];
    s += v; s2 += (double)v * v;
  }
  __shared__ double sd[256], sq[256];
  sd[tid] = s; sq[tid] = s2;
  __syncthreads();
  for (int off = 128; off > 0; off >>= 1) {
    if (tid < off) { sd[tid] += sd[tid + off]; sq[tid] += sq[tid + off]; }
    __syncthreads();
  }
  if (tid == 0) {
    double cnt = (double)(NIMG * HW * HW);
    double mean = sd[0] / cnt;
    double var = sq[0] / cnt - mean * mean;
    double rstd = 1.0 / sqrt(var + 1e-5);
    double g = (double)gamma[c];
    sb[c] = (float)(g * rstd);
    sb[NCH + c] = (float)((double)beta[c] - mean * g * rstd);
  }
}

// Final: out = relu(bn2(t5) + residual x), compact NCHW output.
__global__ __launch_bounds__(256) void final_kernel(
    const float* __restrict__ t5, const float* __restrict__ sb,
    const float* __restrict__ x, float* __restrict__ out) {
  int idx = blockIdx.x * 256 + threadIdx.x;          // 802816 float4 threads
  int f = idx * 4;
  int n = f / (NCH * HW * HW);
  int c = (f / (HW * HW)) % NCH;
  int o = f % (HW * HW);
  int y = o / HW, xc = o % HW;
  const float* tp = t5 + ((size_t)(n * NCH + c) * PADH + y + 1) * PADW + xc + 1;
  float sc = sb[c], bi = sb[NCH + c];
  float4 xv = *(const float4*)(x + f);
  float4 ov;
  ov.x = fmaxf(fmaf(tp[0], sc, bi) + xv.x, 0.0f);
  ov.y = fmaxf(fmaf(tp[1], sc, bi) + xv.y, 0.0f);
  ov.z = fmaxf(fmaf(tp[2], sc, bi) + xv.z, 0.0f);
  ov.w = fmaxf(fmaf(tp[3], sc, bi) + xv.w, 0.0f);
  *(float4*)(out + f) = ov;
}

// ---------------------------------------------------------------------------
extern "C" void kernel_launch(void* const* d_in, const int* in_sizes, int n_in,
                              void* d_out, int out_size, void* d_ws, size_t ws_size,
                              hipStream_t stream) {
  const float* x   = (const float*)d_in[0];
  const float* ws1 = (const float*)d_in[1];
  const float* wa1 = (const float*)d_in[2];
  const float* g1  = (const float*)d_in[3];
  const float* b1  = (const float*)d_in[4];
  const float* ws2 = (const float*)d_in[5];
  const float* wa2 = (const float*)d_in[6];
  const float* g2  = (const float*)d_in[7];
  const float* b2  = (const float*)d_in[8];
  float* out = (float*)d_out;

  float* w = (float*)d_ws;
  unsigned* P1 = (unsigned*)w;               // t1 / t4 (u32 fixed-point padded)
  float* P2 = w + PBUF;                      // t2 / t5 (fp32 padded)
  unsigned short* CL0 = (unsigned short*)(w + 2 * PBUF);  // x  bf16-cl padded
  unsigned short* CL1 = CL0 + PBUF;                       // t3 bf16-cl padded
  float* WAf = w + 3 * PBUF;                 // adder weights u32 x2 (same size)
  unsigned* WA = (unsigned*)WAf;
  unsigned short* WS = (unsigned short*)(WAf + 2 * (size_t)WREL);  // shift bf16 x2
  float* SB1 = WAf + 3 * (size_t)WREL;       // after WS (2*WREL ushorts)
  float* SB2 = SB1 + 256;

  hipLaunchKernelGGL(prep_adder,      dim3(1152), dim3(256), 0, stream, wa1, wa2, WA);
  hipLaunchKernelGGL(prep_shift,      dim3(1152), dim3(256), 0, stream, ws1, ws2, WS);
  hipLaunchKernelGGL(pad_cl,          dim3(960),  dim3(256), 0, stream, x, CL0);
  hipLaunchKernelGGL(zero_halo,       dim3(1920), dim3(256), 0, stream, P1);
  hipLaunchKernelGGL(shift_mfma,      dim3(3136), dim3(256), 0, stream, CL0, WS, P1);            // t1
  hipLaunchKernelGGL(adder_conv,      dim3(784),  dim3(256), 0, stream, P1, WA, P2);             // t2
  hipLaunchKernelGGL(bn_stats,        dim3(128),  dim3(256), 0, stream, P2, g1, b1, SB1);
  hipLaunchKernelGGL(bn_apply_relu_cl,dim3(960),  dim3(256), 0, stream, P2, SB1, CL1);           // t3
  hipLaunchKernelGGL(shift_mfma,      dim3(3136), dim3(256), 0, stream, CL1, WS + WREL, P1);     // t4
  hipLaunchKernelGGL(adder_conv,      dim3(784),  dim3(256), 0, stream, P1, WA + WREL, P2);      // t5
  hipLaunchKernelGGL(bn_stats,        dim3(128),  dim3(256), 0, stream, P2, g2, b2, SB2);
  hipLaunchKernelGGL(final_kernel,    dim3(3136), dim3(256), 0, stream, P2, SB2, x, out);
}

// Round 12
// 582.741 us; speedup vs baseline: 1.7601x; 1.0990x over previous
//
#include <hip/hip_runtime.h>

// Padded layouts (halos zero):
//   fp32 [N][C][30][32]  : adder OUTPUTS (t2/t5)
//   u32  [N][C][30][32]  : adder INPUTS (t1/t4), fixed-point q = rn((v+16)*2^16)
//   bf16 [N][30][32][128]: MFMA inputs (x, t3) channel-last
#define PADH 30
#define PADW 32
#define CSTR (PADH*PADW)            // 960 elems per channel
#define NIMG 32
#define NCH  128
#define HW   28
#define PBUF ((size_t)NIMG*NCH*CSTR)   // 3,932,160
#define WREL (128*128*9)               // 147456 weights per tensor

#define QSCALE 65536.0f
#define QINV  (-1.52587890625e-05f)    // -1/65536 (adder output is negated sum)
#define QZERO 1048576u                 // rn((0+16)*65536)

typedef __attribute__((ext_vector_type(8))) short bf16x8;
typedef __attribute__((ext_vector_type(4))) float f32x4;
typedef __attribute__((ext_vector_type(4))) unsigned u32x4;
// Constant-address-space view: block-uniform address -> compiler emits s_load
// into SGPRs (scalar pipe), not VMEM/LDS.
typedef __attribute__((address_space(4))) const u32x4 cu32x4;

__device__ __forceinline__ unsigned short f2bf(float f) {   // RNE
  unsigned u = __float_as_uint(f);
  return (unsigned short)((u + 0x7FFFu + ((u >> 16) & 1u)) >> 16);
}

// ---------------------------------------------------------------------------
// Adder weights -> [cog32][ci(128)][tap(9)][co4] u32 fixed-point.
__global__ __launch_bounds__(256) void prep_adder(
    const float* __restrict__ a1, const float* __restrict__ a2,
    unsigned* __restrict__ dst) {
  int gid = blockIdx.x * 256 + threadIdx.x;          // 2*147456 threads
  int t = gid / WREL, r = gid % WREL;
  float v = (t ? a2 : a1)[r];
  unsigned q = __float2uint_rn((v + 16.0f) * QSCALE);
  int co = r / 1152, rem = r % 1152;
  int ci = rem / 9, tap = rem % 9;
  int cog = co >> 2, j = co & 3;
  dst[(size_t)t * WREL + (((cog * 128 + ci) * 9 + tap) << 2) + j] = q;
}

// Shift weights: quantize sign*2^round(log2|w|) (zero < 0.005), exact in bf16.
// Layout [cog8][tap9][co16][ci128] bf16 so the MFMA A-frag is one b128/lane.
__global__ __launch_bounds__(256) void prep_shift(
    const float* __restrict__ s1, const float* __restrict__ s2,
    unsigned short* __restrict__ dst) {
  int gid = blockIdx.x * 256 + threadIdx.x;          // 2*147456 threads
  int t = gid / WREL, r = gid % WREL;
  float v = (t ? s2 : s1)[r];
  float aw = fabsf(v);
  if (aw < 0.005f) {
    v = 0.0f;
  } else {
    int e; float m = frexpf(aw, &e);
    int k = (m >= 0.70710678f) ? e : e - 1;          // round(log2 aw)
    v = ldexpf(copysignf(1.0f, v), k);               // exact power of two
  }
  int co = r / 1152, rem = r % 1152;
  int ci = rem / 9, tap = rem % 9;
  int cog = co >> 4, cop = co & 15;
  dst[(size_t)t * WREL + (size_t)((cog * 9 + tap) * 16 + cop) * 128 + ci] = f2bf(v);
}

// ---------------------------------------------------------------------------
// x (compact NCHW fp32) -> channel-last bf16 padded [n][yp30][xp32][ci128].
__global__ __launch_bounds__(256) void pad_cl(
    const float* __restrict__ x, unsigned short* __restrict__ o) {
  __shared__ unsigned short tile[32 * 130];
  int n = blockIdx.x / PADH, yp = blockIdx.x % PADH;
  int tid = threadIdx.x;
  bool rowok = (yp >= 1 && yp <= HW);
#pragma unroll
  for (int it = 0; it < 16; ++it) {
    int idx = it * 256 + tid;                        // xp fast -> coalesced read
    int ci = idx >> 5, xp = idx & 31;
    float v = 0.0f;
    if (rowok && xp >= 1 && xp <= HW)
      v = x[(size_t)(n * NCH + ci) * (HW * HW) + (yp - 1) * HW + (xp - 1)];
    tile[xp * 130 + ci] = f2bf(v);
  }
  __syncthreads();
  unsigned int* ob = (unsigned int*)(o + (size_t)(n * PADH + yp) * PADW * NCH);
#pragma unroll
  for (int it = 0; it < 8; ++it) {
    int uidx = it * 256 + tid;                       // 2048 uints
    int xp = uidx >> 6, cj = uidx & 63;
    ob[xp * 64 + cj] = *(const unsigned int*)&tile[xp * 130 + 2 * cj];
  }
}

// t2 (fp32 padded) -> BN+ReLU -> channel-last bf16 padded (halos zero).
__global__ __launch_bounds__(256) void bn_apply_relu_cl(
    const float* __restrict__ t, const float* __restrict__ sb,
    unsigned short* __restrict__ o) {
  __shared__ unsigned short tile[32 * 130];
  int n = blockIdx.x / PADH, yp = blockIdx.x % PADH;
  int tid = threadIdx.x;
  bool rowok = (yp >= 1 && yp <= HW);
#pragma unroll
  for (int it = 0; it < 16; ++it) {
    int idx = it * 256 + tid;
    int ci = idx >> 5, xp = idx & 31;
    float v = 0.0f;
    if (rowok && xp >= 1 && xp <= HW) {
      float tv = t[((size_t)(n * NCH + ci) * PADH + yp) * PADW + xp];
      v = fmaxf(fmaf(tv, sb[ci], sb[NCH + ci]), 0.0f);
    }
    tile[xp * 130 + ci] = f2bf(v);
  }
  __syncthreads();
  unsigned int* ob = (unsigned int*)(o + (size_t)(n * PADH + yp) * PADW * NCH);
#pragma unroll
  for (int it = 0; it < 8; ++it) {
    int uidx = it * 256 + tid;
    int xp = uidx >> 6, cj = uidx & 63;
    ob[xp * 64 + cj] = *(const unsigned int*)&tile[xp * 130 + 2 * cj];
  }
}

// Zero (quantized) halo cells of the u32 adder-input buffer.
__global__ __launch_bounds__(256) void zero_halo(unsigned* __restrict__ b) {
  int gid = blockIdx.x * 256 + threadIdx.x;          // 4096*120 threads
  int nc = gid / 120, i = gid % 120;
  unsigned* p = b + (size_t)nc * CSTR;
  if (i < 64) {
    int row = (i < 32) ? 0 : (PADH - 1);
    p[row * PADW + (i & 31)] = QZERO;
  } else {
    int i2 = i - 64;
    int row = 1 + (i2 >> 1);
    int col = (i2 & 1) ? (HW + 1) : 0;
    p[row * PADW + col] = QZERO;
  }
}

// ---------------------------------------------------------------------------
// Shift conv on matrix cores; epilogue emits u32 fixed-point for the adder.
__global__ __launch_bounds__(256) void shift_mfma(
    const unsigned short* __restrict__ in, const unsigned short* __restrict__ wq,
    unsigned* __restrict__ out) {
  int wg = blockIdx.x * 4 + (threadIdx.x >> 6);      // 0..12543
  int lane = threadIdx.x & 63;
  int cot = wg & 7;
  int rem = wg >> 3;                                 // 0..1567
  int pxt = rem % 49;
  int n = rem / 49;
  int px = pxt * 16 + (lane & 15);
  int y = px / HW, x = px % HW;
  int kg = lane >> 4;                                // 0..3

  const unsigned short* ibase =
      in + ((size_t)(n * PADH + y + 1) * PADW + (x + 1)) * NCH + kg * 8;
  const unsigned short* wbase =
      wq + ((size_t)(cot * 9) * 16 + (lane & 15)) * NCH + kg * 8;

  f32x4 acc = {0.f, 0.f, 0.f, 0.f};
#pragma unroll
  for (int tap = 0; tap < 9; ++tap) {
    const int ky = tap / 3 - 1, kx = tap % 3 - 1;
    const unsigned short* ib = ibase + (ky * PADW + kx) * NCH;
    const unsigned short* wb = wbase + (size_t)tap * 16 * NCH;
#pragma unroll
    for (int kc = 0; kc < 4; ++kc) {
      bf16x8 a = *(const bf16x8*)(wb + kc * 32);
      bf16x8 b = *(const bf16x8*)(ib + kc * 32);
      acc = __builtin_amdgcn_mfma_f32_16x16x32_bf16(a, b, acc, 0, 0, 0);
    }
  }
  int coa = cot * 16 + (lane >> 4) * 4;
  unsigned* ob = out + ((size_t)(n * NCH + coa) * PADH + (y + 1)) * PADW + (x + 1);
#pragma unroll
  for (int r = 0; r < 4; ++r) {
    float v = fminf(fmaxf(acc[r], -15.9f), 15.9f);   // 16-sigma clamp, unreachable
    ob[r * CSTR] = __float2uint_rn((v + 16.0f) * QSCALE);
  }
}

// ---------------------------------------------------------------------------
// AdderNet conv, integer SAD with SGPR weights: v_sad_u32 vacc, vin, s_w, vacc
// (VOP3: exactly one SGPR source). Thread = 2px x 4co; grid 1568 doubles
// occupancy vs R11 (784-block grid capped waves/CU at 12 -> stalls at
// VALUBusy 55%). Chip-wide SAD and s_load totals unchanged.
__device__ __forceinline__ void sad_op(unsigned& acc, unsigned vin, unsigned w) {
  asm("v_sad_u32 %0, %1, %2, %0" : "+v"(acc) : "v"(vin), "s"(w));
}

__device__ __forceinline__ void load_rows_u(const unsigned* __restrict__ p,
                                            unsigned r[3][4]) {
#pragma unroll
  for (int ky = 0; ky < 3; ++ky) {
    uint2 a = *(const uint2*)(p + ky * PADW);
    uint2 b = *(const uint2*)(p + ky * PADW + 2);
    r[ky][0] = a.x; r[ky][1] = a.y; r[ky][2] = b.x; r[ky][3] = b.y;
  }
}

__device__ __forceinline__ void adder_ci(const unsigned r[3][4],
                                         cu32x4* __restrict__ wv,
                                         unsigned acc[4][2]) {
#pragma unroll
  for (int ky = 0; ky < 3; ++ky)
#pragma unroll
    for (int kx = 0; kx < 3; ++kx) {
      u32x4 wA = wv[ky * 3 + kx];                    // SGPRs (s_load)
#pragma unroll
      for (int p = 0; p < 2; ++p) {
        unsigned v = r[ky][kx + p];
        sad_op(acc[0][p], v, wA.x);
        sad_op(acc[1][p], v, wA.y);
        sad_op(acc[2][p], v, wA.z);
        sad_op(acc[3][p], v, wA.w);
      }
    }
}

__global__ __launch_bounds__(256) void adder_conv(
    const unsigned* __restrict__ in, const unsigned* __restrict__ wr,
    float* __restrict__ out) {
  int bid = blockIdx.x;
  int v = (bid & 7) * 196 + (bid >> 3);              // XCD remap (1568 = 8*196)
  int cog = v & 31;                                  // 32 groups of 4 co
  int chunk = v >> 5;                                // 0..48
  int tid = threadIdx.x;

  int wi = chunk * 256 + tid;                        // 0..12543
  int xh = wi % 14;
  int r2 = wi / 14;
  int y = r2 % 28;
  int n = r2 / 28;
  int x0 = xh << 1;
  const unsigned* ib = in + (size_t)n * NCH * CSTR + y * PADW + x0;
  cu32x4* w4 = (cu32x4*)(wr + (size_t)cog * 4608);   // [ci][9 x u32x4]

  unsigned acc[4][2];
#pragma unroll
  for (int j = 0; j < 4; ++j) { acc[j][0] = 0u; acc[j][1] = 0u; }

  unsigned ra[3][4], rb[3][4];
  load_rows_u(ib, ra);
  for (int ci = 0; ci < 128; ci += 2) {
    load_rows_u(ib + CSTR, rb);
    adder_ci(ra, w4 + (size_t)ci * 9, acc);
    if (ci + 2 < 128) load_rows_u(ib + 2 * CSTR, ra);
    adder_ci(rb, w4 + (size_t)(ci + 1) * 9, acc);
    ib += 2 * CSTR;
  }

  float* ob = out + ((size_t)(n * NCH + (cog << 2)) * PADH + (y + 1)) * PADW + (x0 + 1);
#pragma unroll
  for (int j = 0; j < 4; ++j) {
    ob[j * CSTR + 0] = (float)acc[j][0] * QINV;      // -sum|v-w|
    ob[j * CSTR + 1] = (float)acc[j][1] * QINV;
  }
}

// ---------------------------------------------------------------------------
// BN batch stats (double accum; deterministic). sb[c]=g*rstd, sb[128+c]=b-mean*g*rstd.
__global__ __launch_bounds__(256) void bn_stats(
    const float* __restrict__ t, const float* __restrict__ gamma,
    const float* __restrict__ beta, float* __restrict__ sb) {
  int c = blockIdx.x;
  int tid = threadIdx.x;
  double s = 0.0, s2 = 0.0;
  for (int i = tid; i < NIMG * HW * HW; i += 256) {
    int n = i / (HW * HW);
    int rem = i % (HW * HW);
    int r = rem / HW, x = rem % HW;
    float v = t[((size_t)(n * NCH + c) * PADH + r + 1) * PADW + x + 1];
    s += v; s2 += (double)v * v;
  }
  __shared__ double sd[256], sq[256];
  sd[tid] = s; sq[tid] = s2;
  __syncthreads();
  for (int off = 128; off > 0; off >>= 1) {
    if (tid < off) { sd[tid] += sd[tid + off]; sq[tid] += sq[tid + off]; }
    __syncthreads();
  }
  if (tid == 0) {
    double cnt = (double)(NIMG * HW * HW);
    double mean = sd[0] / cnt;
    double var = sq[0] / cnt - mean * mean;
    double rstd = 1.0 / sqrt(var + 1e-5);
    double g = (double)gamma[c];
    sb[c] = (float)(g * rstd);
    sb[NCH + c] = (float)((double)beta[c] - mean * g * rstd);
  }
}

// Final: out = relu(bn2(t5) + residual x), compact NCHW output.
__global__ __launch_bounds__(256) void final_kernel(
    const float* __restrict__ t5, const float* __restrict__ sb,
    const float* __restrict__ x, float* __restrict__ out) {
  int idx = blockIdx.x * 256 + threadIdx.x;          // 802816 float4 threads
  int f = idx * 4;
  int n = f / (NCH * HW * HW);
  int c = (f / (HW * HW)) % NCH;
  int o = f % (HW * HW);
  int y = o / HW, xc = o % HW;
  const float* tp = t5 + ((size_t)(n * NCH + c) * PADH + y + 1) * PADW + xc + 1;
  float sc = sb[c], bi = sb[NCH + c];
  float4 xv = *(const float4*)(x + f);
  float4 ov;
  ov.x = fmaxf(fmaf(tp[0], sc, bi) + xv.x, 0.0f);
  ov.y = fmaxf(fmaf(tp[1], sc, bi) + xv.y, 0.0f);
  ov.z = fmaxf(fmaf(tp[2], sc, bi) + xv.z, 0.0f);
  ov.w = fmaxf(fmaf(tp[3], sc, bi) + xv.w, 0.0f);
  *(float4*)(out + f) = ov;
}

// ---------------------------------------------------------------------------
extern "C" void kernel_launch(void* const* d_in, const int* in_sizes, int n_in,
                              void* d_out, int out_size, void* d_ws, size_t ws_size,
                              hipStream_t stream) {
  const float* x   = (const float*)d_in[0];
  const float* ws1 = (const float*)d_in[1];
  const float* wa1 = (const float*)d_in[2];
  const float* g1  = (const float*)d_in[3];
  const float* b1  = (const float*)d_in[4];
  const float* ws2 = (const float*)d_in[5];
  const float* wa2 = (const float*)d_in[6];
  const float* g2  = (const float*)d_in[7];
  const float* b2  = (const float*)d_in[8];
  float* out = (float*)d_out;

  float* w = (float*)d_ws;
  unsigned* P1 = (unsigned*)w;               // t1 / t4 (u32 fixed-point padded)
  float* P2 = w + PBUF;                      // t2 / t5 (fp32 padded)
  unsigned short* CL0 = (unsigned short*)(w + 2 * PBUF);  // x  bf16-cl padded
  unsigned short* CL1 = CL0 + PBUF;                       // t3 bf16-cl padded
  float* WAf = w + 3 * PBUF;                 // adder weights u32 x2 (same size)
  unsigned* WA = (unsigned*)WAf;
  unsigned short* WS = (unsigned short*)(WAf + 2 * (size_t)WREL);  // shift bf16 x2
  float* SB1 = WAf + 3 * (size_t)WREL;       // after WS (2*WREL ushorts)
  float* SB2 = SB1 + 256;

  hipLaunchKernelGGL(prep_adder,      dim3(1152), dim3(256), 0, stream, wa1, wa2, WA);
  hipLaunchKernelGGL(prep_shift,      dim3(1152), dim3(256), 0, stream, ws1, ws2, WS);
  hipLaunchKernelGGL(pad_cl,          dim3(960),  dim3(256), 0, stream, x, CL0);
  hipLaunchKernelGGL(zero_halo,       dim3(1920), dim3(256), 0, stream, P1);
  hipLaunchKernelGGL(shift_mfma,      dim3(3136), dim3(256), 0, stream, CL0, WS, P1);            // t1
  hipLaunchKernelGGL(adder_conv,      dim3(1568), dim3(256), 0, stream, P1, WA, P2);             // t2
  hipLaunchKernelGGL(bn_stats,        dim3(128),  dim3(256), 0, stream, P2, g1, b1, SB1);
  hipLaunchKernelGGL(bn_apply_relu_cl,dim3(960),  dim3(256), 0, stream, P2, SB1, CL1);           // t3
  hipLaunchKernelGGL(shift_mfma,      dim3(3136), dim3(256), 0, stream, CL1, WS + WREL, P1);     // t4
  hipLaunchKernelGGL(adder_conv,      dim3(1568), dim3(256), 0, stream, P1, WA + WREL, P2);      // t5
  hipLaunchKernelGGL(bn_stats,        dim3(128),  dim3(256), 0, stream, P2, g2, b2, SB2);
  hipLaunchKernelGGL(final_kernel,    dim3(3136), dim3(256), 0, stream, P2, SB2, x, out);
}

// Round 13
// 447.281 us; speedup vs baseline: 2.2932x; 1.3029x over previous
//
#include <hip/hip_runtime.h>

// Padded layouts (halos zero):
//   fp32 [N][C][30][32]   : adder OUTPUTS (t2/t5)
//   u32  [N][64][30][32]  : adder INPUTS (t1/t4), PACKED ci-pairs, each u16
//                           fixed-point q = rn((v+8)*4096)
//   bf16 [N][30][32][128] : MFMA inputs (x, t3) channel-last
#define PADH 30
#define PADW 32
#define CSTR (PADH*PADW)            // 960 elems per channel(-pair)
#define NIMG 32
#define NCH  128
#define HW   28
#define PBUF ((size_t)NIMG*NCH*CSTR)   // 3,932,160
#define WREL (128*128*9)               // 147456 weights per tensor
#define WPACK (WREL/2)                 // 73728 packed u32 per adder tensor

#define QS16   4096.0f
#define QINV16 (-2.44140625e-04f)      // -1/4096 (adder output is negated sum)
#define QZERO16 0x80008000u            // packed pair of rn(8*4096)=32768

typedef __attribute__((ext_vector_type(8))) short bf16x8;
typedef __attribute__((ext_vector_type(4))) float f32x4;
typedef __attribute__((ext_vector_type(4))) unsigned u32x4;
// Constant-address-space view: block-uniform address -> compiler emits s_load
// into SGPRs (scalar pipe), not VMEM/LDS.
typedef __attribute__((address_space(4))) const u32x4 cu32x4;

__device__ __forceinline__ unsigned short f2bf(float f) {   // RNE
  unsigned u = __float_as_uint(f);
  return (unsigned short)((u + 0x7FFFu + ((u >> 16) & 1u)) >> 16);
}

// ---------------------------------------------------------------------------
// Adder weights -> [cog32][cipair(64)][tap(9)][co4] u32, each = packed u16
// pair (ci even in lo, ci odd in hi).
__global__ __launch_bounds__(256) void prep_adder(
    const float* __restrict__ a1, const float* __restrict__ a2,
    unsigned* __restrict__ dst) {
  int gid = blockIdx.x * 256 + threadIdx.x;          // 2*73728 threads
  int t = gid / WPACK, r = gid % WPACK;
  const float* src = t ? a2 : a1;
  int co = r / 576;                                  // 64 pairs * 9 taps
  int rem = r % 576;
  int pair = rem / 9, tap = rem % 9;
  float v0 = src[co * 1152 + (2 * pair) * 9 + tap];
  float v1 = src[co * 1152 + (2 * pair + 1) * 9 + tap];
  unsigned q0 = __float2uint_rn((v0 + 8.0f) * QS16);
  unsigned q1 = __float2uint_rn((v1 + 8.0f) * QS16);
  int cog = co >> 2, j = co & 3;
  dst[(size_t)t * WPACK + (((cog * 64 + pair) * 9 + tap) << 2) + j] = q0 | (q1 << 16);
}

// Shift weights: quantize sign*2^round(log2|w|) (zero < 0.005), exact in bf16.
// Layout [cog8][tap9][co16][ci128] bf16 so the MFMA A-frag is one b128/lane.
__global__ __launch_bounds__(256) void prep_shift(
    const float* __restrict__ s1, const float* __restrict__ s2,
    unsigned short* __restrict__ dst) {
  int gid = blockIdx.x * 256 + threadIdx.x;          // 2*147456 threads
  int t = gid / WREL, r = gid % WREL;
  float v = (t ? s2 : s1)[r];
  float aw = fabsf(v);
  if (aw < 0.005f) {
    v = 0.0f;
  } else {
    int e; float m = frexpf(aw, &e);
    int k = (m >= 0.70710678f) ? e : e - 1;          // round(log2 aw)
    v = ldexpf(copysignf(1.0f, v), k);               // exact power of two
  }
  int co = r / 1152, rem = r % 1152;
  int ci = rem / 9, tap = rem % 9;
  int cog = co >> 4, cop = co & 15;
  dst[(size_t)t * WREL + (size_t)((cog * 9 + tap) * 16 + cop) * 128 + ci] = f2bf(v);
}

// ---------------------------------------------------------------------------
// x (compact NCHW fp32) -> channel-last bf16 padded [n][yp30][xp32][ci128].
__global__ __launch_bounds__(256) void pad_cl(
    const float* __restrict__ x, unsigned short* __restrict__ o) {
  __shared__ unsigned short tile[32 * 130];
  int n = blockIdx.x / PADH, yp = blockIdx.x % PADH;
  int tid = threadIdx.x;
  bool rowok = (yp >= 1 && yp <= HW);
#pragma unroll
  for (int it = 0; it < 16; ++it) {
    int idx = it * 256 + tid;                        // xp fast -> coalesced read
    int ci = idx >> 5, xp = idx & 31;
    float v = 0.0f;
    if (rowok && xp >= 1 && xp <= HW)
      v = x[(size_t)(n * NCH + ci) * (HW * HW) + (yp - 1) * HW + (xp - 1)];
    tile[xp * 130 + ci] = f2bf(v);
  }
  __syncthreads();
  unsigned int* ob = (unsigned int*)(o + (size_t)(n * PADH + yp) * PADW * NCH);
#pragma unroll
  for (int it = 0; it < 8; ++it) {
    int uidx = it * 256 + tid;                       // 2048 uints
    int xp = uidx >> 6, cj = uidx & 63;
    ob[xp * 64 + cj] = *(const unsigned int*)&tile[xp * 130 + 2 * cj];
  }
}

// t2 (fp32 padded) -> BN+ReLU -> channel-last bf16 padded (halos zero).
__global__ __launch_bounds__(256) void bn_apply_relu_cl(
    const float* __restrict__ t, const float* __restrict__ sb,
    unsigned short* __restrict__ o) {
  __shared__ unsigned short tile[32 * 130];
  int n = blockIdx.x / PADH, yp = blockIdx.x % PADH;
  int tid = threadIdx.x;
  bool rowok = (yp >= 1 && yp <= HW);
#pragma unroll
  for (int it = 0; it < 16; ++it) {
    int idx = it * 256 + tid;
    int ci = idx >> 5, xp = idx & 31;
    float v = 0.0f;
    if (rowok && xp >= 1 && xp <= HW) {
      float tv = t[((size_t)(n * NCH + ci) * PADH + yp) * PADW + xp];
      v = fmaxf(fmaf(tv, sb[ci], sb[NCH + ci]), 0.0f);
    }
    tile[xp * 130 + ci] = f2bf(v);
  }
  __syncthreads();
  unsigned int* ob = (unsigned int*)(o + (size_t)(n * PADH + yp) * PADW * NCH);
#pragma unroll
  for (int it = 0; it < 8; ++it) {
    int uidx = it * 256 + tid;
    int xp = uidx >> 6, cj = uidx & 63;
    ob[xp * 64 + cj] = *(const unsigned int*)&tile[xp * 130 + 2 * cj];
  }
}

// Zero (quantized) halo cells of the packed u32 adder-input buffer.
__global__ __launch_bounds__(256) void zero_halo(unsigned* __restrict__ b) {
  int gid = blockIdx.x * 256 + threadIdx.x;          // 2048*120 threads
  int nc = gid / 120, i = gid % 120;                 // nc over N*64 pairs
  unsigned* p = b + (size_t)nc * CSTR;
  if (i < 64) {
    int row = (i < 32) ? 0 : (PADH - 1);
    p[row * PADW + (i & 31)] = QZERO16;
  } else {
    int i2 = i - 64;
    int row = 1 + (i2 >> 1);
    int col = (i2 & 1) ? (HW + 1) : 0;
    p[row * PADW + col] = QZERO16;
  }
}

// ---------------------------------------------------------------------------
// Shift conv on matrix cores; epilogue emits packed u16-pair fixed point.
__global__ __launch_bounds__(256) void shift_mfma(
    const unsigned short* __restrict__ in, const unsigned short* __restrict__ wq,
    unsigned* __restrict__ out) {
  int wg = blockIdx.x * 4 + (threadIdx.x >> 6);      // 0..12543
  int lane = threadIdx.x & 63;
  int cot = wg & 7;
  int rem = wg >> 3;                                 // 0..1567
  int pxt = rem % 49;
  int n = rem / 49;
  int px = pxt * 16 + (lane & 15);
  int y = px / HW, x = px % HW;
  int kg = lane >> 4;                                // 0..3

  const unsigned short* ibase =
      in + ((size_t)(n * PADH + y + 1) * PADW + (x + 1)) * NCH + kg * 8;
  const unsigned short* wbase =
      wq + ((size_t)(cot * 9) * 16 + (lane & 15)) * NCH + kg * 8;

  f32x4 acc = {0.f, 0.f, 0.f, 0.f};
#pragma unroll
  for (int tap = 0; tap < 9; ++tap) {
    const int ky = tap / 3 - 1, kx = tap % 3 - 1;
    const unsigned short* ib = ibase + (ky * PADW + kx) * NCH;
    const unsigned short* wb = wbase + (size_t)tap * 16 * NCH;
#pragma unroll
    for (int kc = 0; kc < 4; ++kc) {
      bf16x8 a = *(const bf16x8*)(wb + kc * 32);
      bf16x8 b = *(const bf16x8*)(ib + kc * 32);
      acc = __builtin_amdgcn_mfma_f32_16x16x32_bf16(a, b, acc, 0, 0, 0);
    }
  }
  int coa = cot * 16 + (lane >> 4) * 4;              // 4 consecutive co
  unsigned q[4];
#pragma unroll
  for (int r = 0; r < 4; ++r) {
    float v = fminf(fmaxf(acc[r], -7.9f), 7.9f);     // ~8-sigma clamp
    q[r] = __float2uint_rn((v + 8.0f) * QS16);
  }
  int cp = coa >> 1;                                 // channel-pair index
  unsigned* ob = out + ((size_t)(n * 64 + cp) * PADH + (y + 1)) * PADW + (x + 1);
  ob[0] = q[0] | (q[1] << 16);
  ob[CSTR] = q[2] | (q[3] << 16);
}

// ---------------------------------------------------------------------------
// AdderNet conv, packed u16 SAD: v_sad_u16 does TWO |a-b| terms per full-rate
// instr (lo16 + hi16 + acc). Weights in SGPRs (VOP3 allows one SGPR source).
__device__ __forceinline__ void sad16_op(unsigned& acc, unsigned vin, unsigned w) {
  asm("v_sad_u16 %0, %1, %2, %0" : "+v"(acc) : "v"(vin), "s"(w));
}

__device__ __forceinline__ void load_rows_u(const unsigned* __restrict__ p,
                                            unsigned r[3][4]) {
#pragma unroll
  for (int ky = 0; ky < 3; ++ky) {
    uint2 a = *(const uint2*)(p + ky * PADW);
    uint2 b = *(const uint2*)(p + ky * PADW + 2);
    r[ky][0] = a.x; r[ky][1] = a.y; r[ky][2] = b.x; r[ky][3] = b.y;
  }
}

__device__ __forceinline__ void adder_ci(const unsigned r[3][4],
                                         cu32x4* __restrict__ wv,
                                         unsigned acc[4][2]) {
#pragma unroll
  for (int ky = 0; ky < 3; ++ky)
#pragma unroll
    for (int kx = 0; kx < 3; ++kx) {
      u32x4 wA = wv[ky * 3 + kx];                    // SGPRs (s_load)
#pragma unroll
      for (int p = 0; p < 2; ++p) {
        unsigned v = r[ky][kx + p];
        sad16_op(acc[0][p], v, wA.x);
        sad16_op(acc[1][p], v, wA.y);
        sad16_op(acc[2][p], v, wA.z);
        sad16_op(acc[3][p], v, wA.w);
      }
    }
}

__global__ __launch_bounds__(256) void adder_conv(
    const unsigned* __restrict__ in, const unsigned* __restrict__ wr,
    float* __restrict__ out) {
  int bid = blockIdx.x;
  int v = (bid & 7) * 196 + (bid >> 3);              // XCD remap (1568 = 8*196)
  int cog = v & 31;                                  // 32 groups of 4 co
  int chunk = v >> 5;                                // 0..48
  int tid = threadIdx.x;

  int wi = chunk * 256 + tid;                        // 0..12543
  int xh = wi % 14;
  int r2 = wi / 14;
  int y = r2 % 28;
  int n = r2 / 28;
  int x0 = xh << 1;
  const unsigned* ib = in + (size_t)n * 64 * CSTR + y * PADW + x0;  // ci-pair 0
  cu32x4* w4 = (cu32x4*)(wr + (size_t)cog * 2304);   // [cipair][9 x u32x4]

  unsigned acc[4][2];
#pragma unroll
  for (int j = 0; j < 4; ++j) { acc[j][0] = 0u; acc[j][1] = 0u; }

  unsigned ra[3][4], rb[3][4];
  load_rows_u(ib, ra);
  for (int cp = 0; cp < 64; cp += 2) {
    load_rows_u(ib + CSTR, rb);
    adder_ci(ra, w4 + (size_t)cp * 9, acc);
    if (cp + 2 < 64) load_rows_u(ib + 2 * CSTR, ra);
    adder_ci(rb, w4 + (size_t)(cp + 1) * 9, acc);
    ib += 2 * CSTR;
  }

  float* ob = out + ((size_t)(n * NCH + (cog << 2)) * PADH + (y + 1)) * PADW + (x0 + 1);
#pragma unroll
  for (int j = 0; j < 4; ++j) {
    ob[j * CSTR + 0] = (float)acc[j][0] * QINV16;    // -sum|v-w|
    ob[j * CSTR + 1] = (float)acc[j][1] * QINV16;
  }
}

// ---------------------------------------------------------------------------
// BN batch stats (double accum; deterministic). sb[c]=g*rstd, sb[128+c]=b-mean*g*rstd.
__global__ __launch_bounds__(256) void bn_stats(
    const float* __restrict__ t, const float* __restrict__ gamma,
    const float* __restrict__ beta, float* __restrict__ sb) {
  int c = blockIdx.x;
  int tid = threadIdx.x;
  double s = 0.0, s2 = 0.0;
  for (int i = tid; i < NIMG * HW * HW; i += 256) {
    int n = i / (HW * HW);
    int rem = i % (HW * HW);
    int r = rem / HW, x = rem % HW;
    float v = t[((size_t)(n * NCH + c) * PADH + r + 1) * PADW + x + 1];
    s += v; s2 += (double)v * v;
  }
  __shared__ double sd[256], sq[256];
  sd[tid] = s; sq[tid] = s2;
  __syncthreads();
  for (int off = 128; off > 0; off >>= 1) {
    if (tid < off) { sd[tid] += sd[tid + off]; sq[tid] += sq[tid + off]; }
    __syncthreads();
  }
  if (tid == 0) {
    double cnt = (double)(NIMG * HW * HW);
    double mean = sd[0] / cnt;
    double var = sq[0] / cnt - mean * mean;
    double rstd = 1.0 / sqrt(var + 1e-5);
    double g = (double)gamma[c];
    sb[c] = (float)(g * rstd);
    sb[NCH + c] = (float)((double)beta[c] - mean * g * rstd);
  }
}

// Final: out = relu(bn2(t5) + residual x), compact NCHW output.
__global__ __launch_bounds__(256) void final_kernel(
    const float* __restrict__ t5, const float* __restrict__ sb,
    const float* __restrict__ x, float* __restrict__ out) {
  int idx = blockIdx.x * 256 + threadIdx.x;          // 802816 float4 threads
  int f = idx * 4;
  int n = f / (NCH * HW * HW);
  int c = (f / (HW * HW)) % NCH;
  int o = f % (HW * HW);
  int y = o / HW, xc = o % HW;
  const float* tp = t5 + ((size_t)(n * NCH + c) * PADH + y + 1) * PADW + xc + 1;
  float sc = sb[c], bi = sb[NCH + c];
  float4 xv = *(const float4*)(x + f);
  float4 ov;
  ov.x = fmaxf(fmaf(tp[0], sc, bi) + xv.x, 0.0f);
  ov.y = fmaxf(fmaf(tp[1], sc, bi) + xv.y, 0.0f);
  ov.z = fmaxf(fmaf(tp[2], sc, bi) + xv.z, 0.0f);
  ov.w = fmaxf(fmaf(tp[3], sc, bi) + xv.w, 0.0f);
  *(float4*)(out + f) = ov;
}

// ---------------------------------------------------------------------------
extern "C" void kernel_launch(void* const* d_in, const int* in_sizes, int n_in,
                              void* d_out, int out_size, void* d_ws, size_t ws_size,
                              hipStream_t stream) {
  const float* x   = (const float*)d_in[0];
  const float* ws1 = (const float*)d_in[1];
  const float* wa1 = (const float*)d_in[2];
  const float* g1  = (const float*)d_in[3];
  const float* b1  = (const float*)d_in[4];
  const float* ws2 = (const float*)d_in[5];
  const float* wa2 = (const float*)d_in[6];
  const float* g2  = (const float*)d_in[7];
  const float* b2  = (const float*)d_in[8];
  float* out = (float*)d_out;

  float* w = (float*)d_ws;
  unsigned* P1 = (unsigned*)w;               // t1 / t4 (packed u16-pairs, PBUF/2 u32 used)
  float* P2 = w + PBUF;                      // t2 / t5 (fp32 padded)
  unsigned short* CL0 = (unsigned short*)(w + 2 * PBUF);  // x  bf16-cl padded
  unsigned short* CL1 = CL0 + PBUF;                       // t3 bf16-cl padded
  float* WAf = w + 3 * PBUF;                 // adder packed weights x2
  unsigned* WA = (unsigned*)WAf;
  unsigned short* WS = (unsigned short*)(WAf + 2 * (size_t)WREL);  // shift bf16 x2
  float* SB1 = WAf + 3 * (size_t)WREL;       // after WS (2*WREL ushorts)
  float* SB2 = SB1 + 256;

  hipLaunchKernelGGL(prep_adder,      dim3(576),  dim3(256), 0, stream, wa1, wa2, WA);
  hipLaunchKernelGGL(prep_shift,      dim3(1152), dim3(256), 0, stream, ws1, ws2, WS);
  hipLaunchKernelGGL(pad_cl,          dim3(960),  dim3(256), 0, stream, x, CL0);
  hipLaunchKernelGGL(zero_halo,       dim3(960),  dim3(256), 0, stream, P1);
  hipLaunchKernelGGL(shift_mfma,      dim3(3136), dim3(256), 0, stream, CL0, WS, P1);            // t1
  hipLaunchKernelGGL(adder_conv,      dim3(1568), dim3(256), 0, stream, P1, WA, P2);             // t2
  hipLaunchKernelGGL(bn_stats,        dim3(128),  dim3(256), 0, stream, P2, g1, b1, SB1);
  hipLaunchKernelGGL(bn_apply_relu_cl,dim3(960),  dim3(256), 0, stream, P2, SB1, CL1);           // t3
  hipLaunchKernelGGL(shift_mfma,      dim3(3136), dim3(256), 0, stream, CL1, WS + WREL, P1);     // t4
  hipLaunchKernelGGL(adder_conv,      dim3(1568), dim3(256), 0, stream, P1, WA + WPACK, P2);     // t5
  hipLaunchKernelGGL(bn_stats,        dim3(128),  dim3(256), 0, stream, P2, g2, b2, SB2);
  hipLaunchKernelGGL(final_kernel,    dim3(3136), dim3(256), 0, stream, P2, SB2, x, out);
}

// Round 14
// 348.458 us; speedup vs baseline: 2.9435x; 1.2836x over previous
//
#include <hip/hip_runtime.h>

// Padded layouts (halos zero):
//   fp32 [N][C][30][32]        : adder OUTPUTS (t2/t5)
//   u32  [N][64][30][32]       : adder INPUTS (t1/t4), packed u16 ci-pairs,
//                                q = rn((v+8)*4096)
//   bf16 [n][yp30][kc4][xp32][ci32] : MFMA inputs (x, t3) -- k-block-minor so
//                                     every wave fragment load is 1KB contiguous
#define PADH 30
#define PADW 32
#define CSTR (PADH*PADW)            // 960 elems per channel(-pair)
#define NIMG 32
#define NCH  128
#define HW   28
#define PBUF ((size_t)NIMG*NCH*CSTR)   // 3,932,160
#define WREL (128*128*9)               // 147456 weights per tensor
#define WPACK (WREL/2)                 // 73728 packed u32 per adder tensor

#define QS16   4096.0f
#define QINV16 (-2.44140625e-04f)      // -1/4096 (adder output is negated sum)
#define QZERO16 0x80008000u            // packed pair of rn(8*4096)=32768

typedef __attribute__((ext_vector_type(8))) short bf16x8;
typedef __attribute__((ext_vector_type(4))) float f32x4;
typedef __attribute__((ext_vector_type(4))) unsigned u32x4;
// Constant-address-space view: block-uniform address -> compiler emits s_load
// into SGPRs (scalar pipe), not VMEM/LDS.
typedef __attribute__((address_space(4))) const u32x4 cu32x4;

__device__ __forceinline__ unsigned short f2bf(float f) {   // RNE
  unsigned u = __float_as_uint(f);
  return (unsigned short)((u + 0x7FFFu + ((u >> 16) & 1u)) >> 16);
}

// ---------------------------------------------------------------------------
// Adder weights -> [cog32][cipair(64)][tap(9)][co4] u32 packed u16 pairs.
__global__ __launch_bounds__(256) void prep_adder(
    const float* __restrict__ a1, const float* __restrict__ a2,
    unsigned* __restrict__ dst) {
  int gid = blockIdx.x * 256 + threadIdx.x;          // 2*73728 threads
  int t = gid / WPACK, r = gid % WPACK;
  const float* src = t ? a2 : a1;
  int co = r / 576;                                  // 64 pairs * 9 taps
  int rem = r % 576;
  int pair = rem / 9, tap = rem % 9;
  float v0 = src[co * 1152 + (2 * pair) * 9 + tap];
  float v1 = src[co * 1152 + (2 * pair + 1) * 9 + tap];
  unsigned q0 = __float2uint_rn((v0 + 8.0f) * QS16);
  unsigned q1 = __float2uint_rn((v1 + 8.0f) * QS16);
  int cog = co >> 2, j = co & 3;
  dst[(size_t)t * WPACK + (((cog * 64 + pair) * 9 + tap) << 2) + j] = q0 | (q1 << 16);
}

// Shift weights: quantize sign*2^round(log2|w|) (zero < 0.005), exact in bf16.
// Layout [cog8][tap9][kc4][co16][ci32]: wave A-frag = 1KB contiguous.
__global__ __launch_bounds__(256) void prep_shift(
    const float* __restrict__ s1, const float* __restrict__ s2,
    unsigned short* __restrict__ dst) {
  int gid = blockIdx.x * 256 + threadIdx.x;          // 2*147456 threads
  int t = gid / WREL, r = gid % WREL;
  float v = (t ? s2 : s1)[r];
  float aw = fabsf(v);
  if (aw < 0.005f) {
    v = 0.0f;
  } else {
    int e; float m = frexpf(aw, &e);
    int k = (m >= 0.70710678f) ? e : e - 1;          // round(log2 aw)
    v = ldexpf(copysignf(1.0f, v), k);               // exact power of two
  }
  int co = r / 1152, rem = r % 1152;
  int ci = rem / 9, tap = rem % 9;
  int cog = co >> 4, cop = co & 15;
  dst[(size_t)t * WREL +
      ((((size_t)(cog * 9 + tap) * 4 + (ci >> 5)) * 16 + cop) * 32 + (ci & 31))] = f2bf(v);
}

// ---------------------------------------------------------------------------
// x (compact NCHW fp32) -> bf16 padded [n][yp][kc4][xp32][ci32].
__global__ __launch_bounds__(256) void pad_cl(
    const float* __restrict__ x, unsigned short* __restrict__ o) {
  __shared__ unsigned short tile[32 * 130];
  int n = blockIdx.x / PADH, yp = blockIdx.x % PADH;
  int tid = threadIdx.x;
  bool rowok = (yp >= 1 && yp <= HW);
#pragma unroll
  for (int it = 0; it < 16; ++it) {
    int idx = it * 256 + tid;                        // xp fast -> coalesced read
    int ci = idx >> 5, xp = idx & 31;
    float v = 0.0f;
    if (rowok && xp >= 1 && xp <= HW)
      v = x[(size_t)(n * NCH + ci) * (HW * HW) + (yp - 1) * HW + (xp - 1)];
    tile[xp * 130 + ci] = f2bf(v);
  }
  __syncthreads();
  unsigned int* ob = (unsigned int*)(o + (size_t)(n * PADH + yp) * 4096);
#pragma unroll
  for (int it = 0; it < 8; ++it) {
    int uidx = it * 256 + tid;                       // [kc4][xp32][cp16] linear
    int kc = uidx >> 9, xp = (uidx >> 4) & 31, cp = uidx & 15;
    int ci = kc * 32 + 2 * cp;
    ob[uidx] = *(const unsigned int*)&tile[xp * 130 + ci];
  }
}

// t2 (fp32 padded) -> BN+ReLU -> bf16 padded [n][yp][kc4][xp32][ci32].
__global__ __launch_bounds__(256) void bn_apply_relu_cl(
    const float* __restrict__ t, const float* __restrict__ sb,
    unsigned short* __restrict__ o) {
  __shared__ unsigned short tile[32 * 130];
  int n = blockIdx.x / PADH, yp = blockIdx.x % PADH;
  int tid = threadIdx.x;
  bool rowok = (yp >= 1 && yp <= HW);
#pragma unroll
  for (int it = 0; it < 16; ++it) {
    int idx = it * 256 + tid;
    int ci = idx >> 5, xp = idx & 31;
    float v = 0.0f;
    if (rowok && xp >= 1 && xp <= HW) {
      float tv = t[((size_t)(n * NCH + ci) * PADH + yp) * PADW + xp];
      v = fmaxf(fmaf(tv, sb[ci], sb[NCH + ci]), 0.0f);
    }
    tile[xp * 130 + ci] = f2bf(v);
  }
  __syncthreads();
  unsigned int* ob = (unsigned int*)(o + (size_t)(n * PADH + yp) * 4096);
#pragma unroll
  for (int it = 0; it < 8; ++it) {
    int uidx = it * 256 + tid;
    int kc = uidx >> 9, xp = (uidx >> 4) & 31, cp = uidx & 15;
    int ci = kc * 32 + 2 * cp;
    ob[uidx] = *(const unsigned int*)&tile[xp * 130 + ci];
  }
}

// Zero (quantized) halo cells of the packed u32 adder-input buffer.
__global__ __launch_bounds__(256) void zero_halo(unsigned* __restrict__ b) {
  int gid = blockIdx.x * 256 + threadIdx.x;          // 2048*120 threads
  int nc = gid / 120, i = gid % 120;                 // nc over N*64 pairs
  unsigned* p = b + (size_t)nc * CSTR;
  if (i < 64) {
    int row = (i < 32) ? 0 : (PADH - 1);
    p[row * PADW + (i & 31)] = QZERO16;
  } else {
    int i2 = i - 64;
    int row = 1 + (i2 >> 1);
    int col = (i2 & 1) ? (HW + 1) : 0;
    p[row * PADW + col] = QZERO16;
  }
}

// ---------------------------------------------------------------------------
// Shift conv on matrix cores. All fragment loads are 1KB-contiguous wave
// accesses (k-block-minor layouts). XCD-bijective swizzle: 3136 = 8*392,
// each XCD covers 4 images (~1MB input + 294KB weights < 4MiB L2).
__global__ __launch_bounds__(256) void shift_mfma(
    const unsigned short* __restrict__ in, const unsigned short* __restrict__ wq,
    unsigned* __restrict__ out) {
  int bid = blockIdx.x;
  int vb = (bid & 7) * 392 + (bid >> 3);             // bijective remap
  int wg = vb * 4 + (threadIdx.x >> 6);              // 0..12543
  int lane = threadIdx.x & 63;
  int cot = wg & 7;
  int rem = wg >> 3;                                 // 0..1567
  int pxt = rem % 49;
  int n = rem / 49;
  int px = pxt * 16 + (lane & 15);
  int y = px / HW, x = px % HW;
  int kg = lane >> 4;                                // 0..3

  // in: [n][yp][kc][xp][ci32]; shorts: yp stride 4096, kc 1024, xp 32
  const unsigned short* ibase =
      in + ((size_t)(n * PADH + y + 1) * 4096) + (x + 1) * 32 + kg * 8;
  // wq: [cog][tap][kc][co16][ci32]; shorts: cog 18432, tap 2048, kc 512
  const unsigned short* wbase =
      wq + (size_t)cot * 18432 + (lane & 15) * 32 + kg * 8;

  f32x4 acc = {0.f, 0.f, 0.f, 0.f};
#pragma unroll
  for (int tap = 0; tap < 9; ++tap) {
    const int ky = tap / 3 - 1, kx = tap % 3 - 1;
    const unsigned short* ib = ibase + ky * 4096 + kx * 32;
    const unsigned short* wb = wbase + tap * 2048;
#pragma unroll
    for (int kc = 0; kc < 4; ++kc) {
      bf16x8 a = *(const bf16x8*)(wb + kc * 512);
      bf16x8 b = *(const bf16x8*)(ib + kc * 1024);
      acc = __builtin_amdgcn_mfma_f32_16x16x32_bf16(a, b, acc, 0, 0, 0);
    }
  }
  int coa = cot * 16 + (lane >> 4) * 4;              // 4 consecutive co
  unsigned q[4];
#pragma unroll
  for (int r = 0; r < 4; ++r) {
    float v = fminf(fmaxf(acc[r], -7.9f), 7.9f);     // ~8-sigma clamp
    q[r] = __float2uint_rn((v + 8.0f) * QS16);
  }
  int cp = coa >> 1;                                 // channel-pair index
  unsigned* ob = out + ((size_t)(n * 64 + cp) * PADH + (y + 1)) * PADW + (x + 1);
  ob[0] = q[0] | (q[1] << 16);
  ob[CSTR] = q[2] | (q[3] << 16);
}

// ---------------------------------------------------------------------------
// AdderNet conv, packed u16 SAD: v_sad_u16 does TWO |a-b| terms per full-rate
// instr. Weights in SGPRs (VOP3 allows one SGPR source).
__device__ __forceinline__ void sad16_op(unsigned& acc, unsigned vin, unsigned w) {
  asm("v_sad_u16 %0, %1, %2, %0" : "+v"(acc) : "v"(vin), "s"(w));
}

__device__ __forceinline__ void load_rows_u(const unsigned* __restrict__ p,
                                            unsigned r[3][4]) {
#pragma unroll
  for (int ky = 0; ky < 3; ++ky) {
    uint2 a = *(const uint2*)(p + ky * PADW);
    uint2 b = *(const uint2*)(p + ky * PADW + 2);
    r[ky][0] = a.x; r[ky][1] = a.y; r[ky][2] = b.x; r[ky][3] = b.y;
  }
}

__device__ __forceinline__ void adder_ci(const unsigned r[3][4],
                                         cu32x4* __restrict__ wv,
                                         unsigned acc[4][2]) {
#pragma unroll
  for (int ky = 0; ky < 3; ++ky)
#pragma unroll
    for (int kx = 0; kx < 3; ++kx) {
      u32x4 wA = wv[ky * 3 + kx];                    // SGPRs (s_load)
#pragma unroll
      for (int p = 0; p < 2; ++p) {
        unsigned v = r[ky][kx + p];
        sad16_op(acc[0][p], v, wA.x);
        sad16_op(acc[1][p], v, wA.y);
        sad16_op(acc[2][p], v, wA.z);
        sad16_op(acc[3][p], v, wA.w);
      }
    }
}

__global__ __launch_bounds__(256) void adder_conv(
    const unsigned* __restrict__ in, const unsigned* __restrict__ wr,
    float* __restrict__ out) {
  int bid = blockIdx.x;
  int v = (bid & 7) * 196 + (bid >> 3);              // XCD remap (1568 = 8*196)
  int cog = v & 31;                                  // 32 groups of 4 co
  int chunk = v >> 5;                                // 0..48
  int tid = threadIdx.x;

  int wi = chunk * 256 + tid;                        // 0..12543
  int xh = wi % 14;
  int r2 = wi / 14;
  int y = r2 % 28;
  int n = r2 / 28;
  int x0 = xh << 1;
  const unsigned* ib = in + (size_t)n * 64 * CSTR + y * PADW + x0;  // ci-pair 0
  cu32x4* w4 = (cu32x4*)(wr + (size_t)cog * 2304);   // [cipair][9 x u32x4]

  unsigned acc[4][2];
#pragma unroll
  for (int j = 0; j < 4; ++j) { acc[j][0] = 0u; acc[j][1] = 0u; }

  unsigned ra[3][4], rb[3][4];
  load_rows_u(ib, ra);
  for (int cp = 0; cp < 64; cp += 2) {
    load_rows_u(ib + CSTR, rb);
    adder_ci(ra, w4 + (size_t)cp * 9, acc);
    if (cp + 2 < 64) load_rows_u(ib + 2 * CSTR, ra);
    adder_ci(rb, w4 + (size_t)(cp + 1) * 9, acc);
    ib += 2 * CSTR;
  }

  float* ob = out + ((size_t)(n * NCH + (cog << 2)) * PADH + (y + 1)) * PADW + (x0 + 1);
#pragma unroll
  for (int j = 0; j < 4; ++j) {
    ob[j * CSTR + 0] = (float)acc[j][0] * QINV16;    // -sum|v-w|
    ob[j * CSTR + 1] = (float)acc[j][1] * QINV16;
  }
}

// ---------------------------------------------------------------------------
// BN batch stats (double accum; deterministic). sb[c]=g*rstd, sb[128+c]=b-mean*g*rstd.
__global__ __launch_bounds__(256) void bn_stats(
    const float* __restrict__ t, const float* __restrict__ gamma,
    const float* __restrict__ beta, float* __restrict__ sb) {
  int c = blockIdx.x;
  int tid = threadIdx.x;
  double s = 0.0, s2 = 0.0;
  for (int i = tid; i < NIMG * HW * HW; i += 256) {
    int n = i / (HW * HW);
    int rem = i % (HW * HW);
    int r = rem / HW, x = rem % HW;
    float v = t[((size_t)(n * NCH + c) * PADH + r + 1) * PADW + x + 1];
    s += v; s2 += (double)v * v;
  }
  __shared__ double sd[256], sq[256];
  sd[tid] = s; sq[tid] = s2;
  __syncthreads();
  for (int off = 128; off > 0; off >>= 1) {
    if (tid < off) { sd[tid] += sd[tid + off]; sq[tid] += sq[tid + off]; }
    __syncthreads();
  }
  if (tid == 0) {
    double cnt = (double)(NIMG * HW * HW);
    double mean = sd[0] / cnt;
    double var = sq[0] / cnt - mean * mean;
    double rstd = 1.0 / sqrt(var + 1e-5);
    double g = (double)gamma[c];
    sb[c] = (float)(g * rstd);
    sb[NCH + c] = (float)((double)beta[c] - mean * g * rstd);
  }
}

// Final: out = relu(bn2(t5) + residual x), compact NCHW output.
__global__ __launch_bounds__(256) void final_kernel(
    const float* __restrict__ t5, const float* __restrict__ sb,
    const float* __restrict__ x, float* __restrict__ out) {
  int idx = blockIdx.x * 256 + threadIdx.x;          // 802816 float4 threads
  int f = idx * 4;
  int n = f / (NCH * HW * HW);
  int c = (f / (HW * HW)) % NCH;
  int o = f % (HW * HW);
  int y = o / HW, xc = o % HW;
  const float* tp = t5 + ((size_t)(n * NCH + c) * PADH + y + 1) * PADW + xc + 1;
  float sc = sb[c], bi = sb[NCH + c];
  float4 xv = *(const float4*)(x + f);
  float4 ov;
  ov.x = fmaxf(fmaf(tp[0], sc, bi) + xv.x, 0.0f);
  ov.y = fmaxf(fmaf(tp[1], sc, bi) + xv.y, 0.0f);
  ov.z = fmaxf(fmaf(tp[2], sc, bi) + xv.z, 0.0f);
  ov.w = fmaxf(fmaf(tp[3], sc, bi) + xv.w, 0.0f);
  *(float4*)(out + f) = ov;
}

// ---------------------------------------------------------------------------
extern "C" void kernel_launch(void* const* d_in, const int* in_sizes, int n_in,
                              void* d_out, int out_size, void* d_ws, size_t ws_size,
                              hipStream_t stream) {
  const float* x   = (const float*)d_in[0];
  const float* ws1 = (const float*)d_in[1];
  const float* wa1 = (const float*)d_in[2];
  const float* g1  = (const float*)d_in[3];
  const float* b1  = (const float*)d_in[4];
  const float* ws2 = (const float*)d_in[5];
  const float* wa2 = (const float*)d_in[6];
  const float* g2  = (const float*)d_in[7];
  const float* b2  = (const float*)d_in[8];
  float* out = (float*)d_out;

  float* w = (float*)d_ws;
  unsigned* P1 = (unsigned*)w;               // t1 / t4 (packed u16-pairs)
  float* P2 = w + PBUF;                      // t2 / t5 (fp32 padded)
  unsigned short* CL0 = (unsigned short*)(w + 2 * PBUF);  // x  bf16 k-minor
  unsigned short* CL1 = CL0 + PBUF;                       // t3 bf16 k-minor
  float* WAf = w + 3 * PBUF;                 // adder packed weights x2
  unsigned* WA = (unsigned*)WAf;
  unsigned short* WS = (unsigned short*)(WAf + 2 * (size_t)WREL);  // shift bf16 x2
  float* SB1 = WAf + 3 * (size_t)WREL;       // after WS (2*WREL ushorts)
  float* SB2 = SB1 + 256;

  hipLaunchKernelGGL(prep_adder,      dim3(576),  dim3(256), 0, stream, wa1, wa2, WA);
  hipLaunchKernelGGL(prep_shift,      dim3(1152), dim3(256), 0, stream, ws1, ws2, WS);
  hipLaunchKernelGGL(pad_cl,          dim3(960),  dim3(256), 0, stream, x, CL0);
  hipLaunchKernelGGL(zero_halo,       dim3(960),  dim3(256), 0, stream, P1);
  hipLaunchKernelGGL(shift_mfma,      dim3(3136), dim3(256), 0, stream, CL0, WS, P1);            // t1
  hipLaunchKernelGGL(adder_conv,      dim3(1568), dim3(256), 0, stream, P1, WA, P2);             // t2
  hipLaunchKernelGGL(bn_stats,        dim3(128),  dim3(256), 0, stream, P2, g1, b1, SB1);
  hipLaunchKernelGGL(bn_apply_relu_cl,dim3(960),  dim3(256), 0, stream, P2, SB1, CL1);           // t3
  hipLaunchKernelGGL(shift_mfma,      dim3(3136), dim3(256), 0, stream, CL1, WS + WREL, P1);     // t4
  hipLaunchKernelGGL(adder_conv,      dim3(1568), dim3(256), 0, stream, P1, WA + WPACK, P2);     // t5
  hipLaunchKernelGGL(bn_stats,        dim3(128),  dim3(256), 0, stream, P2, g2, b2, SB2);
  hipLaunchKernelGGL(final_kernel,    dim3(3136), dim3(256), 0, stream, P2, SB2, x, out);
}

// Round 15
// 345.579 us; speedup vs baseline: 2.9681x; 1.0083x over previous
//
#include <hip/hip_runtime.h>

// Padded layouts (halos zero):
//   fp32 [N][C][30][32]        : adder OUTPUTS (t2/t5)
//   u32  [N][64][30][32]       : adder INPUTS (t1/t4), packed u16 ci-pairs,
//                                q = rn((v+8)*4096)
//   bf16 [n][yp30][kc4][xp32][ci32] : MFMA inputs (x, t3) -- k-block-minor so
//                                     every wave fragment load is 1KB contiguous
#define PADH 30
#define PADW 32
#define CSTR (PADH*PADW)            // 960 elems per channel(-pair)
#define NIMG 32
#define NCH  128
#define HW   28
#define PBUF ((size_t)NIMG*NCH*CSTR)   // 3,932,160
#define WREL (128*128*9)               // 147456 weights per tensor
#define WPACK (WREL/2)                 // 73728 packed u32 per adder tensor

#define QS16   4096.0f
#define QINV16 (-2.44140625e-04f)      // -1/4096 (adder output is negated sum)
#define QZERO16 0x80008000u            // packed pair of rn(8*4096)=32768

typedef __attribute__((ext_vector_type(8))) short bf16x8;
typedef __attribute__((ext_vector_type(4))) float f32x4;
typedef __attribute__((ext_vector_type(4))) unsigned u32x4;
// Constant-address-space view: block-uniform address -> compiler emits s_load
// into SGPRs (scalar pipe), not VMEM/LDS.
typedef __attribute__((address_space(4))) const u32x4 cu32x4;

__device__ __forceinline__ unsigned short f2bf(float f) {   // RNE
  unsigned u = __float_as_uint(f);
  return (unsigned short)((u + 0x7FFFu + ((u >> 16) & 1u)) >> 16);
}

// ---------------------------------------------------------------------------
// Adder weights -> [cog32][cipair(64)][tap(9)][co4] u32 packed u16 pairs.
__global__ __launch_bounds__(256) void prep_adder(
    const float* __restrict__ a1, const float* __restrict__ a2,
    unsigned* __restrict__ dst) {
  int gid = blockIdx.x * 256 + threadIdx.x;          // 2*73728 threads
  int t = gid / WPACK, r = gid % WPACK;
  const float* src = t ? a2 : a1;
  int co = r / 576;                                  // 64 pairs * 9 taps
  int rem = r % 576;
  int pair = rem / 9, tap = rem % 9;
  float v0 = src[co * 1152 + (2 * pair) * 9 + tap];
  float v1 = src[co * 1152 + (2 * pair + 1) * 9 + tap];
  unsigned q0 = __float2uint_rn((v0 + 8.0f) * QS16);
  unsigned q1 = __float2uint_rn((v1 + 8.0f) * QS16);
  int cog = co >> 2, j = co & 3;
  dst[(size_t)t * WPACK + (((cog * 64 + pair) * 9 + tap) << 2) + j] = q0 | (q1 << 16);
}

// Shift weights: quantize sign*2^round(log2|w|) (zero < 0.005), exact in bf16.
// Layout [cog8][tap9][kc4][co16][ci32]: wave A-frag = 1KB contiguous.
__global__ __launch_bounds__(256) void prep_shift(
    const float* __restrict__ s1, const float* __restrict__ s2,
    unsigned short* __restrict__ dst) {
  int gid = blockIdx.x * 256 + threadIdx.x;          // 2*147456 threads
  int t = gid / WREL, r = gid % WREL;
  float v = (t ? s2 : s1)[r];
  float aw = fabsf(v);
  if (aw < 0.005f) {
    v = 0.0f;
  } else {
    int e; float m = frexpf(aw, &e);
    int k = (m >= 0.70710678f) ? e : e - 1;          // round(log2 aw)
    v = ldexpf(copysignf(1.0f, v), k);               // exact power of two
  }
  int co = r / 1152, rem = r % 1152;
  int ci = rem / 9, tap = rem % 9;
  int cog = co >> 4, cop = co & 15;
  dst[(size_t)t * WREL +
      ((((size_t)(cog * 9 + tap) * 4 + (ci >> 5)) * 16 + cop) * 32 + (ci & 31))] = f2bf(v);
}

// ---------------------------------------------------------------------------
// x (compact NCHW fp32) -> bf16 padded [n][yp][kc4][xp32][ci32].
__global__ __launch_bounds__(256) void pad_cl(
    const float* __restrict__ x, unsigned short* __restrict__ o) {
  __shared__ unsigned short tile[32 * 130];
  int n = blockIdx.x / PADH, yp = blockIdx.x % PADH;
  int tid = threadIdx.x;
  bool rowok = (yp >= 1 && yp <= HW);
#pragma unroll
  for (int it = 0; it < 16; ++it) {
    int idx = it * 256 + tid;                        // xp fast -> coalesced read
    int ci = idx >> 5, xp = idx & 31;
    float v = 0.0f;
    if (rowok && xp >= 1 && xp <= HW)
      v = x[(size_t)(n * NCH + ci) * (HW * HW) + (yp - 1) * HW + (xp - 1)];
    tile[xp * 130 + ci] = f2bf(v);
  }
  __syncthreads();
  unsigned int* ob = (unsigned int*)(o + (size_t)(n * PADH + yp) * 4096);
#pragma unroll
  for (int it = 0; it < 8; ++it) {
    int uidx = it * 256 + tid;                       // [kc4][xp32][cp16] linear
    int kc = uidx >> 9, xp = (uidx >> 4) & 31, cp = uidx & 15;
    int ci = kc * 32 + 2 * cp;
    ob[uidx] = *(const unsigned int*)&tile[xp * 130 + ci];
  }
}

// t2 (fp32 padded) -> BN+ReLU -> bf16 padded [n][yp][kc4][xp32][ci32].
__global__ __launch_bounds__(256) void bn_apply_relu_cl(
    const float* __restrict__ t, const float* __restrict__ sb,
    unsigned short* __restrict__ o) {
  __shared__ unsigned short tile[32 * 130];
  int n = blockIdx.x / PADH, yp = blockIdx.x % PADH;
  int tid = threadIdx.x;
  bool rowok = (yp >= 1 && yp <= HW);
#pragma unroll
  for (int it = 0; it < 16; ++it) {
    int idx = it * 256 + tid;
    int ci = idx >> 5, xp = idx & 31;
    float v = 0.0f;
    if (rowok && xp >= 1 && xp <= HW) {
      float tv = t[((size_t)(n * NCH + ci) * PADH + yp) * PADW + xp];
      v = fmaxf(fmaf(tv, sb[ci], sb[NCH + ci]), 0.0f);
    }
    tile[xp * 130 + ci] = f2bf(v);
  }
  __syncthreads();
  unsigned int* ob = (unsigned int*)(o + (size_t)(n * PADH + yp) * 4096);
#pragma unroll
  for (int it = 0; it < 8; ++it) {
    int uidx = it * 256 + tid;
    int kc = uidx >> 9, xp = (uidx >> 4) & 31, cp = uidx & 15;
    int ci = kc * 32 + 2 * cp;
    ob[uidx] = *(const unsigned int*)&tile[xp * 130 + ci];
  }
}

// Zero (quantized) halo cells of the packed u32 adder-input buffer.
__global__ __launch_bounds__(256) void zero_halo(unsigned* __restrict__ b) {
  int gid = blockIdx.x * 256 + threadIdx.x;          // 2048*120 threads
  int nc = gid / 120, i = gid % 120;                 // nc over N*64 pairs
  unsigned* p = b + (size_t)nc * CSTR;
  if (i < 64) {
    int row = (i < 32) ? 0 : (PADH - 1);
    p[row * PADW + (i & 31)] = QZERO16;
  } else {
    int i2 = i - 64;
    int row = 1 + (i2 >> 1);
    int col = (i2 & 1) ? (HW + 1) : 0;
    p[row * PADW + col] = QZERO16;
  }
}

// ---------------------------------------------------------------------------
// Shift conv on matrix cores. All fragment loads are 1KB-contiguous wave
// accesses (k-block-minor layouts). XCD-bijective swizzle: 3136 = 8*392.
__global__ __launch_bounds__(256) void shift_mfma(
    const unsigned short* __restrict__ in, const unsigned short* __restrict__ wq,
    unsigned* __restrict__ out) {
  int bid = blockIdx.x;
  int vb = (bid & 7) * 392 + (bid >> 3);             // bijective remap
  int wg = vb * 4 + (threadIdx.x >> 6);              // 0..12543
  int lane = threadIdx.x & 63;
  int cot = wg & 7;
  int rem = wg >> 3;                                 // 0..1567
  int pxt = rem % 49;
  int n = rem / 49;
  int px = pxt * 16 + (lane & 15);
  int y = px / HW, x = px % HW;
  int kg = lane >> 4;                                // 0..3

  // in: [n][yp][kc][xp][ci32]; shorts: yp stride 4096, kc 1024, xp 32
  const unsigned short* ibase =
      in + ((size_t)(n * PADH + y + 1) * 4096) + (x + 1) * 32 + kg * 8;
  // wq: [cog][tap][kc][co16][ci32]; shorts: cog 18432, tap 2048, kc 512
  const unsigned short* wbase =
      wq + (size_t)cot * 18432 + (lane & 15) * 32 + kg * 8;

  f32x4 acc = {0.f, 0.f, 0.f, 0.f};
#pragma unroll
  for (int tap = 0; tap < 9; ++tap) {
    const int ky = tap / 3 - 1, kx = tap % 3 - 1;
    const unsigned short* ib = ibase + ky * 4096 + kx * 32;
    const unsigned short* wb = wbase + tap * 2048;
#pragma unroll
    for (int kc = 0; kc < 4; ++kc) {
      bf16x8 a = *(const bf16x8*)(wb + kc * 512);
      bf16x8 b = *(const bf16x8*)(ib + kc * 1024);
      acc = __builtin_amdgcn_mfma_f32_16x16x32_bf16(a, b, acc, 0, 0, 0);
    }
  }
  int coa = cot * 16 + (lane >> 4) * 4;              // 4 consecutive co
  unsigned q[4];
#pragma unroll
  for (int r = 0; r < 4; ++r) {
    float v = fminf(fmaxf(acc[r], -7.9f), 7.9f);     // ~8-sigma clamp
    q[r] = __float2uint_rn((v + 8.0f) * QS16);
  }
  int cp = coa >> 1;                                 // channel-pair index
  unsigned* ob = out + ((size_t)(n * 64 + cp) * PADH + (y + 1)) * PADW + (x + 1);
  ob[0] = q[0] | (q[1] << 16);
  ob[CSTR] = q[2] | (q[3] << 16);
}

// ---------------------------------------------------------------------------
// AdderNet conv, packed u16 SAD: v_sad_u16 does TWO |a-b| terms per full-rate
// instr. Weights in SGPRs via constant-AS s_load, DOUBLE-BUFFERED one ci-pair
// ahead (R14 PMC: SGPR_Count=64 -> no prefetch, ~200cyc SMEM latency exposed
// per 144cyc of SAD issue -> VALUBusy 60%). Two 9xu32x4 sets = 72 SGPRs.
__device__ __forceinline__ void sad16_op(unsigned& acc, unsigned vin, unsigned w) {
  asm("v_sad_u16 %0, %1, %2, %0" : "+v"(acc) : "v"(vin), "s"(w));
}

__device__ __forceinline__ void load_rows_u(const unsigned* __restrict__ p,
                                            unsigned r[3][4]) {
#pragma unroll
  for (int ky = 0; ky < 3; ++ky) {
    uint2 a = *(const uint2*)(p + ky * PADW);
    uint2 b = *(const uint2*)(p + ky * PADW + 2);
    r[ky][0] = a.x; r[ky][1] = a.y; r[ky][2] = b.x; r[ky][3] = b.y;
  }
}

__device__ __forceinline__ void adder_ci_reg(const unsigned r[3][4],
                                             const u32x4 w[9],
                                             unsigned acc[4][2]) {
#pragma unroll
  for (int ky = 0; ky < 3; ++ky)
#pragma unroll
    for (int kx = 0; kx < 3; ++kx) {
      u32x4 wA = w[ky * 3 + kx];                     // already in SGPRs
#pragma unroll
      for (int p = 0; p < 2; ++p) {
        unsigned v = r[ky][kx + p];
        sad16_op(acc[0][p], v, wA.x);
        sad16_op(acc[1][p], v, wA.y);
        sad16_op(acc[2][p], v, wA.z);
        sad16_op(acc[3][p], v, wA.w);
      }
    }
}

__global__ __launch_bounds__(256) void adder_conv(
    const unsigned* __restrict__ in, const unsigned* __restrict__ wr,
    float* __restrict__ out) {
  int bid = blockIdx.x;
  int v = (bid & 7) * 196 + (bid >> 3);              // XCD remap (1568 = 8*196)
  int cog = v & 31;                                  // 32 groups of 4 co
  int chunk = v >> 5;                                // 0..48
  int tid = threadIdx.x;

  int wi = chunk * 256 + tid;                        // 0..12543
  int xh = wi % 14;
  int r2 = wi / 14;
  int y = r2 % 28;
  int n = r2 / 28;
  int x0 = xh << 1;
  const unsigned* ib = in + (size_t)n * 64 * CSTR + y * PADW + x0;  // ci-pair 0
  cu32x4* w4 = (cu32x4*)(wr + (size_t)cog * 2304);   // [cipair][9 x u32x4]

  unsigned acc[4][2];
#pragma unroll
  for (int j = 0; j < 4; ++j) { acc[j][0] = 0u; acc[j][1] = 0u; }

  u32x4 cw[9], nw[9];
#pragma unroll
  for (int t = 0; t < 9; ++t) cw[t] = w4[t];         // ci-pair 0 weights
  unsigned ra[3][4], rb[3][4];
  load_rows_u(ib, ra);

  for (int cp = 0; cp < 64; cp += 2) {
#pragma unroll
    for (int t = 0; t < 9; ++t) nw[t] = w4[(cp + 1) * 9 + t];   // prefetch cp+1
    load_rows_u(ib + CSTR, rb);
    adder_ci_reg(ra, cw, acc);                       // compute cp (uses cw)
    if (cp + 2 < 64) {
#pragma unroll
      for (int t = 0; t < 9; ++t) cw[t] = w4[(cp + 2) * 9 + t]; // prefetch cp+2
      load_rows_u(ib + 2 * CSTR, ra);
    }
    adder_ci_reg(rb, nw, acc);                       // compute cp+1 (uses nw)
    ib += 2 * CSTR;
  }

  float* ob = out + ((size_t)(n * NCH + (cog << 2)) * PADH + (y + 1)) * PADW + (x0 + 1);
#pragma unroll
  for (int j = 0; j < 4; ++j) {
    ob[j * CSTR + 0] = (float)acc[j][0] * QINV16;    // -sum|v-w|
    ob[j * CSTR + 1] = (float)acc[j][1] * QINV16;
  }
}

// ---------------------------------------------------------------------------
// BN batch stats (double accum; deterministic). sb[c]=g*rstd, sb[128+c]=b-mean*g*rstd.
__global__ __launch_bounds__(256) void bn_stats(
    const float* __restrict__ t, const float* __restrict__ gamma,
    const float* __restrict__ beta, float* __restrict__ sb) {
  int c = blockIdx.x;
  int tid = threadIdx.x;
  double s = 0.0, s2 = 0.0;
  for (int i = tid; i < NIMG * HW * HW; i += 256) {
    int n = i / (HW * HW);
    int rem = i % (HW * HW);
    int r = rem / HW, x = rem % HW;
    float v = t[((size_t)(n * NCH + c) * PADH + r + 1) * PADW + x + 1];
    s += v; s2 += (double)v * v;
  }
  __shared__ double sd[256], sq[256];
  sd[tid] = s; sq[tid] = s2;
  __syncthreads();
  for (int off = 128; off > 0; off >>= 1) {
    if (tid < off) { sd[tid] += sd[tid + off]; sq[tid] += sq[tid + off]; }
    __syncthreads();
  }
  if (tid == 0) {
    double cnt = (double)(NIMG * HW * HW);
    double mean = sd[0] / cnt;
    double var = sq[0] / cnt - mean * mean;
    double rstd = 1.0 / sqrt(var + 1e-5);
    double g = (double)gamma[c];
    sb[c] = (float)(g * rstd);
    sb[NCH + c] = (float)((double)beta[c] - mean * g * rstd);
  }
}

// Final: out = relu(bn2(t5) + residual x), compact NCHW output.
__global__ __launch_bounds__(256) void final_kernel(
    const float* __restrict__ t5, const float* __restrict__ sb,
    const float* __restrict__ x, float* __restrict__ out) {
  int idx = blockIdx.x * 256 + threadIdx.x;          // 802816 float4 threads
  int f = idx * 4;
  int n = f / (NCH * HW * HW);
  int c = (f / (HW * HW)) % NCH;
  int o = f % (HW * HW);
  int y = o / HW, xc = o % HW;
  const float* tp = t5 + ((size_t)(n * NCH + c) * PADH + y + 1) * PADW + xc + 1;
  float sc = sb[c], bi = sb[NCH + c];
  float4 xv = *(const float4*)(x + f);
  float4 ov;
  ov.x = fmaxf(fmaf(tp[0], sc, bi) + xv.x, 0.0f);
  ov.y = fmaxf(fmaf(tp[1], sc, bi) + xv.y, 0.0f);
  ov.z = fmaxf(fmaf(tp[2], sc, bi) + xv.z, 0.0f);
  ov.w = fmaxf(fmaf(tp[3], sc, bi) + xv.w, 0.0f);
  *(float4*)(out + f) = ov;
}

// ---------------------------------------------------------------------------
extern "C" void kernel_launch(void* const* d_in, const int* in_sizes, int n_in,
                              void* d_out, int out_size, void* d_ws, size_t ws_size,
                              hipStream_t stream) {
  const float* x   = (const float*)d_in[0];
  const float* ws1 = (const float*)d_in[1];
  const float* wa1 = (const float*)d_in[2];
  const float* g1  = (const float*)d_in[3];
  const float* b1  = (const float*)d_in[4];
  const float* ws2 = (const float*)d_in[5];
  const float* wa2 = (const float*)d_in[6];
  const float* g2  = (const float*)d_in[7];
  const float* b2  = (const float*)d_in[8];
  float* out = (float*)d_out;

  float* w = (float*)d_ws;
  unsigned* P1 = (unsigned*)w;               // t1 / t4 (packed u16-pairs)
  float* P2 = w + PBUF;                      // t2 / t5 (fp32 padded)
  unsigned short* CL0 = (unsigned short*)(w + 2 * PBUF);  // x  bf16 k-minor
  unsigned short* CL1 = CL0 + PBUF;                       // t3 bf16 k-minor
  float* WAf = w + 3 * PBUF;                 // adder packed weights x2
  unsigned* WA = (unsigned*)WAf;
  unsigned short* WS = (unsigned short*)(WAf + 2 * (size_t)WREL);  // shift bf16 x2
  float* SB1 = WAf + 3 * (size_t)WREL;       // after WS (2*WREL ushorts)
  float* SB2 = SB1 + 256;

  hipLaunchKernelGGL(prep_adder,      dim3(576),  dim3(256), 0, stream, wa1, wa2, WA);
  hipLaunchKernelGGL(prep_shift,      dim3(1152), dim3(256), 0, stream, ws1, ws2, WS);
  hipLaunchKernelGGL(pad_cl,          dim3(960),  dim3(256), 0, stream, x, CL0);
  hipLaunchKernelGGL(zero_halo,       dim3(960),  dim3(256), 0, stream, P1);
  hipLaunchKernelGGL(shift_mfma,      dim3(3136), dim3(256), 0, stream, CL0, WS, P1);            // t1
  hipLaunchKernelGGL(adder_conv,      dim3(1568), dim3(256), 0, stream, P1, WA, P2);             // t2
  hipLaunchKernelGGL(bn_stats,        dim3(128),  dim3(256), 0, stream, P2, g1, b1, SB1);
  hipLaunchKernelGGL(bn_apply_relu_cl,dim3(960),  dim3(256), 0, stream, P2, SB1, CL1);           // t3
  hipLaunchKernelGGL(shift_mfma,      dim3(3136), dim3(256), 0, stream, CL1, WS + WREL, P1);     // t4
  hipLaunchKernelGGL(adder_conv,      dim3(1568), dim3(256), 0, stream, P1, WA + WPACK, P2);     // t5
  hipLaunchKernelGGL(bn_stats,        dim3(128),  dim3(256), 0, stream, P2, g2, b2, SB2);
  hipLaunchKernelGGL(final_kernel,    dim3(3136), dim3(256), 0, stream, P2, SB2, x, out);
}

// Round 16
// 256.928 us; speedup vs baseline: 3.9922x; 1.3450x over previous
//
#include <hip/hip_runtime.h>

// Padded layouts (halos zero):
//   fp32 [N][C][30][32]        : adder OUTPUTS (t2/t5)
//   u32  [N][64][30][32]       : adder INPUTS (t1/t4), packed u16 ci-pairs,
//                                q = rn((v+8)*4096)
//   bf16 [n][yp30][kc4][xp32][ci32] : MFMA inputs (x, t3) -- k-block-minor so
//                                     every wave fragment load is 1KB contiguous
#define PADH 30
#define PADW 32
#define CSTR (PADH*PADW)            // 960 elems per channel(-pair)
#define NIMG 32
#define NCH  128
#define HW   28
#define PBUF ((size_t)NIMG*NCH*CSTR)   // 3,932,160
#define WREL (128*128*9)               // 147456 weights per tensor
#define WPACK (WREL/2)                 // 73728 packed u32 per adder tensor

#define QS16   4096.0f
#define QINV16 (-2.44140625e-04f)      // -1/4096 (adder output is negated sum)
#define QZERO16 0x80008000u            // packed pair of rn(8*4096)=32768

typedef __attribute__((ext_vector_type(8))) short bf16x8;
typedef __attribute__((ext_vector_type(4))) float f32x4;
typedef __attribute__((ext_vector_type(4))) unsigned u32x4;
// Constant-address-space view: block-uniform address -> compiler emits s_load
// into SGPRs (scalar pipe), not VMEM/LDS.
typedef __attribute__((address_space(4))) const u32x4 cu32x4;

__device__ __forceinline__ unsigned short f2bf(float f) {   // RNE
  unsigned u = __float_as_uint(f);
  return (unsigned short)((u + 0x7FFFu + ((u >> 16) & 1u)) >> 16);
}

// ---------------------------------------------------------------------------
// Adder weights -> [cog32][cipair(64)][tap(9)][co4] u32 packed u16 pairs.
__global__ __launch_bounds__(256) void prep_adder(
    const float* __restrict__ a1, const float* __restrict__ a2,
    unsigned* __restrict__ dst) {
  int gid = blockIdx.x * 256 + threadIdx.x;          // 2*73728 threads
  int t = gid / WPACK, r = gid % WPACK;
  const float* src = t ? a2 : a1;
  int co = r / 576;                                  // 64 pairs * 9 taps
  int rem = r % 576;
  int pair = rem / 9, tap = rem % 9;
  float v0 = src[co * 1152 + (2 * pair) * 9 + tap];
  float v1 = src[co * 1152 + (2 * pair + 1) * 9 + tap];
  unsigned q0 = __float2uint_rn((v0 + 8.0f) * QS16);
  unsigned q1 = __float2uint_rn((v1 + 8.0f) * QS16);
  int cog = co >> 2, j = co & 3;
  dst[(size_t)t * WPACK + (((cog * 64 + pair) * 9 + tap) << 2) + j] = q0 | (q1 << 16);
}

// Shift weights: quantize sign*2^round(log2|w|) (zero < 0.005), exact in bf16.
// Layout [cog8][tap9][kc4][co16][ci32]: wave A-frag = 1KB contiguous.
__global__ __launch_bounds__(256) void prep_shift(
    const float* __restrict__ s1, const float* __restrict__ s2,
    unsigned short* __restrict__ dst) {
  int gid = blockIdx.x * 256 + threadIdx.x;          // 2*147456 threads
  int t = gid / WREL, r = gid % WREL;
  float v = (t ? s2 : s1)[r];
  float aw = fabsf(v);
  if (aw < 0.005f) {
    v = 0.0f;
  } else {
    int e; float m = frexpf(aw, &e);
    int k = (m >= 0.70710678f) ? e : e - 1;          // round(log2 aw)
    v = ldexpf(copysignf(1.0f, v), k);               // exact power of two
  }
  int co = r / 1152, rem = r % 1152;
  int ci = rem / 9, tap = rem % 9;
  int cog = co >> 4, cop = co & 15;
  dst[(size_t)t * WREL +
      ((((size_t)(cog * 9 + tap) * 4 + (ci >> 5)) * 16 + cop) * 32 + (ci & 31))] = f2bf(v);
}

// ---------------------------------------------------------------------------
// x (compact NCHW fp32) -> bf16 padded [n][yp][kc4][xp32][ci32].
__global__ __launch_bounds__(256) void pad_cl(
    const float* __restrict__ x, unsigned short* __restrict__ o) {
  __shared__ unsigned short tile[32 * 130];
  int n = blockIdx.x / PADH, yp = blockIdx.x % PADH;
  int tid = threadIdx.x;
  bool rowok = (yp >= 1 && yp <= HW);
#pragma unroll
  for (int it = 0; it < 16; ++it) {
    int idx = it * 256 + tid;                        // xp fast -> coalesced read
    int ci = idx >> 5, xp = idx & 31;
    float v = 0.0f;
    if (rowok && xp >= 1 && xp <= HW)
      v = x[(size_t)(n * NCH + ci) * (HW * HW) + (yp - 1) * HW + (xp - 1)];
    tile[xp * 130 + ci] = f2bf(v);
  }
  __syncthreads();
  unsigned int* ob = (unsigned int*)(o + (size_t)(n * PADH + yp) * 4096);
#pragma unroll
  for (int it = 0; it < 8; ++it) {
    int uidx = it * 256 + tid;                       // [kc4][xp32][cp16] linear
    int kc = uidx >> 9, xp = (uidx >> 4) & 31, cp = uidx & 15;
    int ci = kc * 32 + 2 * cp;
    ob[uidx] = *(const unsigned int*)&tile[xp * 130 + ci];
  }
}

// t2 (fp32 padded) -> BN+ReLU -> bf16 padded [n][yp][kc4][xp32][ci32].
__global__ __launch_bounds__(256) void bn_apply_relu_cl(
    const float* __restrict__ t, const float* __restrict__ sb,
    unsigned short* __restrict__ o) {
  __shared__ unsigned short tile[32 * 130];
  int n = blockIdx.x / PADH, yp = blockIdx.x % PADH;
  int tid = threadIdx.x;
  bool rowok = (yp >= 1 && yp <= HW);
#pragma unroll
  for (int it = 0; it < 16; ++it) {
    int idx = it * 256 + tid;
    int ci = idx >> 5, xp = idx & 31;
    float v = 0.0f;
    if (rowok && xp >= 1 && xp <= HW) {
      float tv = t[((size_t)(n * NCH + ci) * PADH + yp) * PADW + xp];
      v = fmaxf(fmaf(tv, sb[ci], sb[NCH + ci]), 0.0f);
    }
    tile[xp * 130 + ci] = f2bf(v);
  }
  __syncthreads();
  unsigned int* ob = (unsigned int*)(o + (size_t)(n * PADH + yp) * 4096);
#pragma unroll
  for (int it = 0; it < 8; ++it) {
    int uidx = it * 256 + tid;
    int kc = uidx >> 9, xp = (uidx >> 4) & 31, cp = uidx & 15;
    int ci = kc * 32 + 2 * cp;
    ob[uidx] = *(const unsigned int*)&tile[xp * 130 + ci];
  }
}

// Zero (quantized) halo cells of the packed u32 adder-input buffer.
__global__ __launch_bounds__(256) void zero_halo(unsigned* __restrict__ b) {
  int gid = blockIdx.x * 256 + threadIdx.x;          // 2048*120 threads
  int nc = gid / 120, i = gid % 120;                 // nc over N*64 pairs
  unsigned* p = b + (size_t)nc * CSTR;
  if (i < 64) {
    int row = (i < 32) ? 0 : (PADH - 1);
    p[row * PADW + (i & 31)] = QZERO16;
  } else {
    int i2 = i - 64;
    int row = 1 + (i2 >> 1);
    int col = (i2 & 1) ? (HW + 1) : 0;
    p[row * PADW + col] = QZERO16;
  }
}

// ---------------------------------------------------------------------------
// Shift conv on matrix cores. Block = 512 thr = 8 waves = ALL 8 co-tiles of
// one (n, pxt): the shared input tile (4 padded rows = 32KB) is staged in LDS
// once and re-used by all 8 waves (B global traffic /8; was 1 load per MFMA).
// A wave's tap-fragment read is a contiguous 1KB LDS region -> conflict-free.
// A (weights) stay global (L2-resident, 288KB). Grid 1568 = 8*196 XCD-swz.
__global__ __launch_bounds__(512) void shift_mfma(
    const unsigned short* __restrict__ in, const unsigned short* __restrict__ wq,
    unsigned* __restrict__ out) {
  __shared__ uint4 btile4[2048];                     // 32KB: 4 rows x 8KB
  char* btile = (char*)btile4;
  int bid = blockIdx.x;
  int vb = (bid & 7) * 196 + (bid >> 3);             // bijective (1568 = 8*196)
  int pxt = vb % 49;
  int n = vb / 49;
  int cot = threadIdx.x >> 6;                        // wave id = co-tile 0..7
  int lane = threadIdx.x & 63;
  int t = threadIdx.x;

  int px0 = pxt * 16;
  int y0 = px0 / HW;                                 // logical row of first px
  // stage padded rows y0..y0+3 (logical y0-1..y0+2), row clamped to 29
#pragma unroll
  for (int it = 0; it < 4; ++it) {
    int rp = y0 + it; if (rp > 29) rp = 29;
    const uint4* src = (const uint4*)(in + (size_t)(n * PADH + rp) * 4096) + t;
    *(uint4*)(btile + it * 8192 + t * 16) = *src;
  }
  __syncthreads();

  int px = px0 + (lane & 15);
  int y = px / HW, x = px % HW;
  int iro = y - y0;                                  // 0 or 1
  int colb = (x + 1) * 64 + (lane >> 4) * 16;        // byte offset in row blk
  const unsigned short* wbase =
      wq + (size_t)cot * 18432 + (lane & 15) * 32 + (lane >> 4) * 8;

  f32x4 acc = {0.f, 0.f, 0.f, 0.f};
#pragma unroll
  for (int tap = 0; tap < 9; ++tap) {
    const int ky = tap / 3 - 1, kx = tap % 3 - 1;
    const char* lb = btile + (iro + ky + 1) * 8192 + colb + kx * 64;
    const unsigned short* wb = wbase + tap * 2048;
#pragma unroll
    for (int kc = 0; kc < 4; ++kc) {
      bf16x8 a = *(const bf16x8*)(wb + kc * 512);
      bf16x8 b = *(const bf16x8*)(lb + kc * 2048);
      acc = __builtin_amdgcn_mfma_f32_16x16x32_bf16(a, b, acc, 0, 0, 0);
    }
  }
  int coa = cot * 16 + (lane >> 4) * 4;              // 4 consecutive co
  unsigned q[4];
#pragma unroll
  for (int r = 0; r < 4; ++r) {
    float v = fminf(fmaxf(acc[r], -7.9f), 7.9f);     // ~8-sigma clamp
    q[r] = __float2uint_rn((v + 8.0f) * QS16);
  }
  int cp = coa >> 1;                                 // channel-pair index
  unsigned* ob = out + ((size_t)(n * 64 + cp) * PADH + (y + 1)) * PADW + (x + 1);
  ob[0] = q[0] | (q[1] << 16);
  ob[CSTR] = q[2] | (q[3] << 16);
}

// ---------------------------------------------------------------------------
// AdderNet conv, packed u16 SAD (v_sad_u16: two |a-b| terms per full-rate
// instr). Weights in SGPRs via constant-AS s_load, double-buffered.
__device__ __forceinline__ void sad16_op(unsigned& acc, unsigned vin, unsigned w) {
  asm("v_sad_u16 %0, %1, %2, %0" : "+v"(acc) : "v"(vin), "s"(w));
}

__device__ __forceinline__ void load_rows_u(const unsigned* __restrict__ p,
                                            unsigned r[3][4]) {
#pragma unroll
  for (int ky = 0; ky < 3; ++ky) {
    uint2 a = *(const uint2*)(p + ky * PADW);
    uint2 b = *(const uint2*)(p + ky * PADW + 2);
    r[ky][0] = a.x; r[ky][1] = a.y; r[ky][2] = b.x; r[ky][3] = b.y;
  }
}

__device__ __forceinline__ void adder_ci_reg(const unsigned r[3][4],
                                             const u32x4 w[9],
                                             unsigned acc[4][2]) {
#pragma unroll
  for (int ky = 0; ky < 3; ++ky)
#pragma unroll
    for (int kx = 0; kx < 3; ++kx) {
      u32x4 wA = w[ky * 3 + kx];                     // already in SGPRs
#pragma unroll
      for (int p = 0; p < 2; ++p) {
        unsigned v = r[ky][kx + p];
        sad16_op(acc[0][p], v, wA.x);
        sad16_op(acc[1][p], v, wA.y);
        sad16_op(acc[2][p], v, wA.z);
        sad16_op(acc[3][p], v, wA.w);
      }
    }
}

__global__ __launch_bounds__(256) void adder_conv(
    const unsigned* __restrict__ in, const unsigned* __restrict__ wr,
    float* __restrict__ out) {
  int bid = blockIdx.x;
  int v = (bid & 7) * 196 + (bid >> 3);              // XCD remap (1568 = 8*196)
  int cog = v & 31;                                  // 32 groups of 4 co
  int chunk = v >> 5;                                // 0..48
  int tid = threadIdx.x;

  int wi = chunk * 256 + tid;                        // 0..12543
  int xh = wi % 14;
  int r2 = wi / 14;
  int y = r2 % 28;
  int n = r2 / 28;
  int x0 = xh << 1;
  const unsigned* ib = in + (size_t)n * 64 * CSTR + y * PADW + x0;  // ci-pair 0
  cu32x4* w4 = (cu32x4*)(wr + (size_t)cog * 2304);   // [cipair][9 x u32x4]

  unsigned acc[4][2];
#pragma unroll
  for (int j = 0; j < 4; ++j) { acc[j][0] = 0u; acc[j][1] = 0u; }

  u32x4 cw[9], nw[9];
#pragma unroll
  for (int t = 0; t < 9; ++t) cw[t] = w4[t];         // ci-pair 0 weights
  unsigned ra[3][4], rb[3][4];
  load_rows_u(ib, ra);

  for (int cp = 0; cp < 64; cp += 2) {
#pragma unroll
    for (int t = 0; t < 9; ++t) nw[t] = w4[(cp + 1) * 9 + t];   // prefetch cp+1
    load_rows_u(ib + CSTR, rb);
    adder_ci_reg(ra, cw, acc);                       // compute cp (uses cw)
    if (cp + 2 < 64) {
#pragma unroll
      for (int t = 0; t < 9; ++t) cw[t] = w4[(cp + 2) * 9 + t]; // prefetch cp+2
      load_rows_u(ib + 2 * CSTR, ra);
    }
    adder_ci_reg(rb, nw, acc);                       // compute cp+1 (uses nw)
    ib += 2 * CSTR;
  }

  float* ob = out + ((size_t)(n * NCH + (cog << 2)) * PADH + (y + 1)) * PADW + (x0 + 1);
#pragma unroll
  for (int j = 0; j < 4; ++j) {
    ob[j * CSTR + 0] = (float)acc[j][0] * QINV16;    // -sum|v-w|
    ob[j * CSTR + 1] = (float)acc[j][1] * QINV16;
  }
}

// ---------------------------------------------------------------------------
// BN batch stats, 2-stage (R15: 128-block bn_stats left half the chip idle).
// Stage 1: 1024 blocks = channel x 8 image-slices, double partial sums.
// Stage 2: 1 block x 128 threads, fixed-order sum -> deterministic.
__global__ __launch_bounds__(256) void bn_stats_part(
    const float* __restrict__ t, double* __restrict__ ps) {
  int c = blockIdx.x >> 3, sl = blockIdx.x & 7;
  int tid = threadIdx.x;
  double s = 0.0, s2 = 0.0;
  for (int i = tid; i < 4 * HW * HW; i += 256) {
    int nl = i / (HW * HW);
    int rem = i % (HW * HW);
    int r = rem / HW, x = rem % HW;
    int n = sl * 4 + nl;
    float v = t[((size_t)(n * NCH + c) * PADH + r + 1) * PADW + x + 1];
    s += v; s2 += (double)v * v;
  }
  __shared__ double sd[256], sq[256];
  sd[tid] = s; sq[tid] = s2;
  __syncthreads();
  for (int off = 128; off > 0; off >>= 1) {
    if (tid < off) { sd[tid] += sd[tid + off]; sq[tid] += sq[tid + off]; }
    __syncthreads();
  }
  if (tid == 0) {
    ps[(size_t)blockIdx.x * 2] = sd[0];
    ps[(size_t)blockIdx.x * 2 + 1] = sq[0];
  }
}

__global__ __launch_bounds__(128) void bn_finalize(
    const double* __restrict__ ps, const float* __restrict__ gamma,
    const float* __restrict__ beta, float* __restrict__ sb) {
  int c = threadIdx.x;                               // 0..127
  double s = 0.0, s2 = 0.0;
#pragma unroll
  for (int k = 0; k < 8; ++k) {
    s += ps[(size_t)(c * 8 + k) * 2];
    s2 += ps[(size_t)(c * 8 + k) * 2 + 1];
  }
  double cnt = (double)(NIMG * HW * HW);
  double mean = s / cnt;
  double var = s2 / cnt - mean * mean;
  double rstd = 1.0 / sqrt(var + 1e-5);
  double g = (double)gamma[c];
  sb[c] = (float)(g * rstd);
  sb[NCH + c] = (float)((double)beta[c] - mean * g * rstd);
}

// Final: out = relu(bn2(t5) + residual x), compact NCHW output.
__global__ __launch_bounds__(256) void final_kernel(
    const float* __restrict__ t5, const float* __restrict__ sb,
    const float* __restrict__ x, float* __restrict__ out) {
  int idx = blockIdx.x * 256 + threadIdx.x;          // 802816 float4 threads
  int f = idx * 4;
  int n = f / (NCH * HW * HW);
  int c = (f / (HW * HW)) % NCH;
  int o = f % (HW * HW);
  int y = o / HW, xc = o % HW;
  const float* tp = t5 + ((size_t)(n * NCH + c) * PADH + y + 1) * PADW + xc + 1;
  float sc = sb[c], bi = sb[NCH + c];
  float4 xv = *(const float4*)(x + f);
  float4 ov;
  ov.x = fmaxf(fmaf(tp[0], sc, bi) + xv.x, 0.0f);
  ov.y = fmaxf(fmaf(tp[1], sc, bi) + xv.y, 0.0f);
  ov.z = fmaxf(fmaf(tp[2], sc, bi) + xv.z, 0.0f);
  ov.w = fmaxf(fmaf(tp[3], sc, bi) + xv.w, 0.0f);
  *(float4*)(out + f) = ov;
}

// ---------------------------------------------------------------------------
extern "C" void kernel_launch(void* const* d_in, const int* in_sizes, int n_in,
                              void* d_out, int out_size, void* d_ws, size_t ws_size,
                              hipStream_t stream) {
  const float* x   = (const float*)d_in[0];
  const float* ws1 = (const float*)d_in[1];
  const float* wa1 = (const float*)d_in[2];
  const float* g1  = (const float*)d_in[3];
  const float* b1  = (const float*)d_in[4];
  const float* ws2 = (const float*)d_in[5];
  const float* wa2 = (const float*)d_in[6];
  const float* g2  = (const float*)d_in[7];
  const float* b2  = (const float*)d_in[8];
  float* out = (float*)d_out;

  float* w = (float*)d_ws;
  unsigned* P1 = (unsigned*)w;               // t1 / t4 (packed u16-pairs)
  float* P2 = w + PBUF;                      // t2 / t5 (fp32 padded)
  unsigned short* CL0 = (unsigned short*)(w + 2 * PBUF);  // x  bf16 k-minor
  unsigned short* CL1 = CL0 + PBUF;                       // t3 bf16 k-minor
  float* WAf = w + 3 * PBUF;                 // adder packed weights x2
  unsigned* WA = (unsigned*)WAf;
  unsigned short* WS = (unsigned short*)(WAf + 2 * (size_t)WREL);  // shift bf16 x2
  float* SB1 = WAf + 3 * (size_t)WREL;       // after WS (2*WREL ushorts)
  float* SB2 = SB1 + 256;
  double* PS = (double*)(SB2 + 256);         // 1024 x 2 doubles partials

  hipLaunchKernelGGL(prep_adder,      dim3(576),  dim3(256), 0, stream, wa1, wa2, WA);
  hipLaunchKernelGGL(prep_shift,      dim3(1152), dim3(256), 0, stream, ws1, ws2, WS);
  hipLaunchKernelGGL(pad_cl,          dim3(960),  dim3(256), 0, stream, x, CL0);
  hipLaunchKernelGGL(zero_halo,       dim3(960),  dim3(256), 0, stream, P1);
  hipLaunchKernelGGL(shift_mfma,      dim3(1568), dim3(512), 0, stream, CL0, WS, P1);            // t1
  hipLaunchKernelGGL(adder_conv,      dim3(1568), dim3(256), 0, stream, P1, WA, P2);             // t2
  hipLaunchKernelGGL(bn_stats_part,   dim3(1024), dim3(256), 0, stream, P2, PS);
  hipLaunchKernelGGL(bn_finalize,     dim3(1),    dim3(128), 0, stream, PS, g1, b1, SB1);
  hipLaunchKernelGGL(bn_apply_relu_cl,dim3(960),  dim3(256), 0, stream, P2, SB1, CL1);           // t3
  hipLaunchKernelGGL(shift_mfma,      dim3(1568), dim3(512), 0, stream, CL1, WS + WREL, P1);     // t4
  hipLaunchKernelGGL(adder_conv,      dim3(1568), dim3(256), 0, stream, P1, WA + WPACK, P2);     // t5
  hipLaunchKernelGGL(bn_stats_part,   dim3(1024), dim3(256), 0, stream, P2, PS);
  hipLaunchKernelGGL(bn_finalize,     dim3(1),    dim3(128), 0, stream, PS, g2, b2, SB2);
  hipLaunchKernelGGL(final_kernel,    dim3(3136), dim3(256), 0, stream, P2, SB2, x, out);
}